// Round 3
// baseline (7746.741 us; speedup 1.0000x reference)
//
#include <hip/hip_runtime.h>
#include <hip/hip_bf16.h>
#include <math.h>

#define N_PTS 15872
#define M_PTS 35637
#define KNN_K 5
#define KUP   20
#define JSPLIT 8
#define UP_ROWS (M_PTS * KUP)   // 712740
#define CDIV(a,b) (((a)+(b)-1)/(b))

typedef __hip_bfloat16 bf16;
__device__ __forceinline__ float b2f(bf16 x){ return __bfloat162float(x); }

// ---------------------------------------------------------------------------
// dtype flag: pos_emb[0,0:2] == (0.0, 1.0) exactly in both dtypes.
// first dword == 0x3F800000 <=> packed bf16 (0x0000,0x3F80). fp32 -> 0x00000000.
__global__ void flag_k(const unsigned* __restrict__ pos_raw, int* __restrict__ flag){
  if (threadIdx.x == 0 && blockIdx.x == 0)
    flag[0] = (pos_raw[0] == 0x3F800000u) ? 1 : 0;
}

// convert one param array (bf16 or fp32 per flag) to fp32
__global__ void cvtw_k(const void* __restrict__ src, float* __restrict__ dst, int n,
                       const int* __restrict__ flag){
  int i = blockIdx.x*256 + threadIdx.x;
  if (i >= n) return;
  if (flag[0]) dst[i] = b2f(((const bf16*)src)[i]);
  else         dst[i] = ((const float*)src)[i];
}

__global__ void fillmark_k(bf16* __restrict__ out, int n){
  int i = blockIdx.x*256 + threadIdx.x;
  if (i < n) out[i] = __float2bfloat16(12345.0f);
}

// ---------------------------------------------------------------------------
// Generic fused GEMM (fp32 A, fp32 W):  C[m,n] = ACT( EPI( sum_k A[m,k]*W[n,k] ) )
// EPI 0: v*scale[n]+shift[n]   EPI 1: v+shift[n]   EPI 2: (v+shift[n])*gmul
// ACT 0: none   ACT 1: lrelu(0.2)   ACT 2: sin
// ---------------------------------------------------------------------------
template<int EPI, int ACT>
__global__ __launch_bounds__(256) void gemm_k(
    const float* __restrict__ A, int lda,
    const float* __restrict__ W, int ldw,
    const float* __restrict__ scale, const float* __restrict__ shift,
    float gmul, float* __restrict__ C, int ldc,
    int M, int Nout, int K)
{
  __shared__ __align__(16) float As[16][64];
  __shared__ __align__(16) float Ws[16][64];
  const int tid = threadIdx.x;
  const int tx = tid & 15, ty = tid >> 4;
  const int bm = blockIdx.x * 64, bn = blockIdx.y * 64;
  const int ar = tid >> 2, ak = (tid & 3) * 4;
  float acc[4][4] = {};
  for (int k0 = 0; k0 < K; k0 += 16) {
    float a0=0.f,a1=0.f,a2=0.f,a3=0.f;
    int grow = bm + ar;
    if (grow < M) {
      const float* ap = A + (size_t)grow * lda + (k0 + ak);
      int rem = K - (k0 + ak);
      if (rem >= 4) { a0=ap[0]; a1=ap[1]; a2=ap[2]; a3=ap[3]; }
      else { if(rem>0)a0=ap[0]; if(rem>1)a1=ap[1]; if(rem>2)a2=ap[2]; }
    }
    float w0=0.f,w1=0.f,w2=0.f,w3=0.f;
    int gn = bn + ar;
    if (gn < Nout) {
      const float* wp = W + (size_t)gn * ldw + (k0 + ak);
      int rem = K - (k0 + ak);
      if (rem >= 4) { w0=wp[0]; w1=wp[1]; w2=wp[2]; w3=wp[3]; }
      else { if(rem>0)w0=wp[0]; if(rem>1)w1=wp[1]; if(rem>2)w2=wp[2]; }
    }
    __syncthreads();
    As[ak+0][ar]=a0; As[ak+1][ar]=a1; As[ak+2][ar]=a2; As[ak+3][ar]=a3;
    Ws[ak+0][ar]=w0; Ws[ak+1][ar]=w1; Ws[ak+2][ar]=w2; Ws[ak+3][ar]=w3;
    __syncthreads();
#pragma unroll
    for (int kk = 0; kk < 16; kk++) {
      float4 av = *reinterpret_cast<const float4*>(&As[kk][ty*4]);
      float4 wv = *reinterpret_cast<const float4*>(&Ws[kk][tx*4]);
      float aa[4] = {av.x,av.y,av.z,av.w};
      float ww[4] = {wv.x,wv.y,wv.z,wv.w};
#pragma unroll
      for (int i=0;i<4;i++)
#pragma unroll
        for (int j=0;j<4;j++) acc[i][j] += aa[i]*ww[j];
    }
  }
#pragma unroll
  for (int i=0;i<4;i++){
    int m = bm + ty*4 + i;
    if (m >= M) continue;
#pragma unroll
    for (int j=0;j<4;j++){
      int n = bn + tx*4 + j;
      if (n >= Nout) continue;
      float v = acc[i][j];
      if (EPI==0)      v = v * scale[n] + shift[n];
      else if (EPI==1) v = v + shift[n];
      else             v = (v + shift[n]) * gmul;
      if (ACT==1)      v = v > 0.f ? v : 0.2f*v;
      else if (ACT==2) v = sinf(v);
      C[(size_t)m*ldc + n] = v;
    }
  }
}

// Adaptive-A GEMM: A dtype selected by flag; rowoff = global row offset into A.
template<int EPI, int ACT>
__global__ __launch_bounds__(256) void gemm_ak(
    const void* __restrict__ A, int lda, int rowoff,
    const float* __restrict__ W, int ldw,
    const float* __restrict__ scale, const float* __restrict__ shift,
    float gmul, float* __restrict__ C, int ldc,
    int M, int Nout, int K, const int* __restrict__ flag)
{
  __shared__ __align__(16) float As[16][64];
  __shared__ __align__(16) float Ws[16][64];
  const int isbf = flag[0];
  const int tid = threadIdx.x;
  const int tx = tid & 15, ty = tid >> 4;
  const int bm = blockIdx.x * 64, bn = blockIdx.y * 64;
  const int ar = tid >> 2, ak = (tid & 3) * 4;
  float acc[4][4] = {};
  for (int k0 = 0; k0 < K; k0 += 16) {
    float a0=0.f,a1=0.f,a2=0.f,a3=0.f;
    int grow = bm + ar;
    if (grow < M) {
      size_t base = (size_t)(rowoff + grow) * lda + (k0 + ak);
      int rem = K - (k0 + ak);
      if (isbf) {
        const bf16* ap = (const bf16*)A + base;
        if (rem >= 4) { a0=b2f(ap[0]); a1=b2f(ap[1]); a2=b2f(ap[2]); a3=b2f(ap[3]); }
        else { if(rem>0)a0=b2f(ap[0]); if(rem>1)a1=b2f(ap[1]); if(rem>2)a2=b2f(ap[2]); }
      } else {
        const float* ap = (const float*)A + base;
        if (rem >= 4) { a0=ap[0]; a1=ap[1]; a2=ap[2]; a3=ap[3]; }
        else { if(rem>0)a0=ap[0]; if(rem>1)a1=ap[1]; if(rem>2)a2=ap[2]; }
      }
    }
    float w0=0.f,w1=0.f,w2=0.f,w3=0.f;
    int gn = bn + ar;
    if (gn < Nout) {
      const float* wp = W + (size_t)gn * ldw + (k0 + ak);
      int rem = K - (k0 + ak);
      if (rem >= 4) { w0=wp[0]; w1=wp[1]; w2=wp[2]; w3=wp[3]; }
      else { if(rem>0)w0=wp[0]; if(rem>1)w1=wp[1]; if(rem>2)w2=wp[2]; }
    }
    __syncthreads();
    As[ak+0][ar]=a0; As[ak+1][ar]=a1; As[ak+2][ar]=a2; As[ak+3][ar]=a3;
    Ws[ak+0][ar]=w0; Ws[ak+1][ar]=w1; Ws[ak+2][ar]=w2; Ws[ak+3][ar]=w3;
    __syncthreads();
#pragma unroll
    for (int kk = 0; kk < 16; kk++) {
      float4 av = *reinterpret_cast<const float4*>(&As[kk][ty*4]);
      float4 wv = *reinterpret_cast<const float4*>(&Ws[kk][tx*4]);
      float aa[4] = {av.x,av.y,av.z,av.w};
      float ww[4] = {wv.x,wv.y,wv.z,wv.w};
#pragma unroll
      for (int i=0;i<4;i++)
#pragma unroll
        for (int j=0;j<4;j++) acc[i][j] += aa[i]*ww[j];
    }
  }
#pragma unroll
  for (int i=0;i<4;i++){
    int m = bm + ty*4 + i;
    if (m >= M) continue;
#pragma unroll
    for (int j=0;j<4;j++){
      int n = bn + tx*4 + j;
      if (n >= Nout) continue;
      float v = acc[i][j];
      if (EPI==0)      v = v * scale[n] + shift[n];
      else if (EPI==1) v = v + shift[n];
      else             v = (v + shift[n]) * gmul;
      if (ACT==1)      v = v > 0.f ? v : 0.2f*v;
      else if (ACT==2) v = sinf(v);
      C[(size_t)m*ldc + n] = v;
    }
  }
}

// ---------------------------------------------------------------------------
__global__ void featin_k(const void* __restrict__ ldx, const void* __restrict__ pos,
                         float* __restrict__ xf, const int* __restrict__ flag){
  int i = blockIdx.x*256 + threadIdx.x;
  if (i >= N_PTS*35) return;
  int n = i / 35, c = i % 35;
  float v;
  if (flag[0]) {
    v = (c < 3) ? b2f(((const bf16*)ldx)[n*3+c]) : b2f(((const bf16*)pos)[n*32 + (c-3)]);
  } else {
    v = (c < 3) ? ((const float*)ldx)[n*3+c] : ((const float*)pos)[n*32 + (c-3)];
  }
  xf[(size_t)n*227 + c] = v;
}

__global__ void gather_e_k(const float* __restrict__ xf, int coff, int CIN,
                           const int* __restrict__ idx, float* __restrict__ e,
                           int n0, int np){
  int W2 = 2*CIN;
  int i = blockIdx.x*256 + threadIdx.x;
  if (i >= np*KNN_K*W2) return;
  int c = i % W2; int ek = i / W2;
  int nl = ek / KNN_K, k = ek % KNN_K;
  int n = n0 + nl;
  int j = idx[n*KNN_K + k];
  float out;
  if (c < CIN) out = xf[(size_t)j*227 + coff + c] - xf[(size_t)n*227 + coff + c];
  else         out = xf[(size_t)n*227 + coff + (c-CIN)];
  e[(size_t)ek*W2 + c] = out;
}

__global__ void kmax_k(const float* __restrict__ e2, int C, float* __restrict__ f1,
                       int n0, int np){
  int i = blockIdx.x*256 + threadIdx.x;
  if (i >= np*C) return;
  int nl = i / C, c = i % C;
  float v = -1e30f;
  for (int k=0;k<KNN_K;k++) v = fmaxf(v, e2[((size_t)nl*KNN_K+k)*C + c]);
  f1[(size_t)(n0+nl)*C + c] = v;
}

template<int C>
__global__ __launch_bounds__(256) void reduce1_k(const float* __restrict__ X, int n,
                                                 float* __restrict__ pmax, float* __restrict__ psum){
  const int tid = threadIdx.x;
  const int c = tid % C;
  const int r0 = tid / C;
  const int TPR = 256 / C;
  float vmax = -1e30f, vsum = 0.f;
  for (int row = blockIdx.x * TPR + r0; row < n; row += gridDim.x * TPR) {
    float v = X[(size_t)row * C + c];
    vmax = fmaxf(vmax, v); vsum += v;
  }
  __shared__ float smax[256], ssum[256];
  smax[tid]=vmax; ssum[tid]=vsum;
  __syncthreads();
  if (tid < C) {
    for (int q=1;q<TPR;q++){ vmax=fmaxf(vmax, smax[q*C+c]); vsum += ssum[q*C+c]; }
    pmax[blockIdx.x*C + c] = vmax; psum[blockIdx.x*C + c] = vsum;
  }
}

template<int C>
__global__ void reduce2_k(const float* __restrict__ pmax, const float* __restrict__ psum,
                          int nblk, float invn, float* __restrict__ fmaxo, float* __restrict__ favgo){
  int c = threadIdx.x; if (c >= C) return;
  float vmax=-1e30f, vsum=0.f;
  for (int b=0;b<nblk;b++){ vmax=fmaxf(vmax,pmax[b*C+c]); vsum+=psum[b*C+c]; }
  fmaxo[c]=vmax; favgo[c]=vsum*invn;
}

__global__ void concat_k(const float* __restrict__ xf, int coff, int CF,
                         const float* __restrict__ f1, int C,
                         const float* __restrict__ fmax, const float* __restrict__ favg,
                         float* __restrict__ h, int n0, int np){
  int W = CF + 3*C;
  int i = blockIdx.x*256 + threadIdx.x;
  if (i >= np*W) return;
  int nl = i / W, c = i % W;
  int n = n0 + nl;
  float v;
  if (c < CF)          v = xf[(size_t)n*227 + coff + c];
  else if (c < CF+C)   v = f1[(size_t)n*C + (c-CF)];
  else if (c < CF+2*C) v = fmax[c-CF-C];
  else                 v = favg[c-CF-2*C];
  h[(size_t)nl*W + c] = v;
}

__global__ void norms_k(const float* __restrict__ xf, float* __restrict__ nr){
  int n = blockIdx.x*256 + threadIdx.x;
  if (n >= N_PTS) return;
  const float* p = xf + (size_t)n*227 + 35;
  float s = 0.f;
  for (int d=0;d<64;d++) s += p[d]*p[d];
  nr[n] = s;
}

#define BUBBLE() \
  if (tv4 > tv3){ float tf=tv3; tv3=tv4; tv4=tf; int ti=tj3; tj3=tj4; tj4=ti; } \
  if (tv3 > tv2){ float tf=tv2; tv2=tv3; tv3=tf; int ti=tj2; tj2=tj3; tj3=ti; } \
  if (tv2 > tv1){ float tf=tv1; tv1=tv2; tv2=tf; int ti=tj1; tj1=tj2; tj2=ti; } \
  if (tv1 > tv0){ float tf=tv0; tv0=tv1; tv1=tf; int ti=tj0; tj0=tj1; tj1=ti; }

__global__ __launch_bounds__(256) void knn_k(const float* __restrict__ xf,
                                             const float* __restrict__ nr,
                                             float* __restrict__ candv, int* __restrict__ candi){
  __shared__ __align__(16) float4 sj[128][16];
  __shared__ float snorm[128];
  const int i = blockIdx.x*256 + threadIdx.x;
  const int part = blockIdx.y;
  const int jbeg = part * (N_PTS / JSPLIT);
  const int jend = jbeg + (N_PTS / JSPLIT);
  float4 fr[16];
  {
    const float* p = xf + (size_t)i*227 + 35;
#pragma unroll
    for (int q=0;q<16;q++) fr[q] = make_float4(p[4*q],p[4*q+1],p[4*q+2],p[4*q+3]);
  }
  const float ni = nr[i];
  float tv0=-1e30f,tv1=-1e30f,tv2=-1e30f,tv3=-1e30f,tv4=-1e30f;
  int tj0=0,tj1=0,tj2=0,tj3=0,tj4=0;
  for (int j0 = jbeg; j0 < jend; j0 += 128) {
    __syncthreads();
    for (int u = threadIdx.x; u < 128*64; u += 256) {
      int jj = u >> 6, d = u & 63;
      int j = j0 + jj;
      ((float*)sj)[u] = (j < jend) ? xf[(size_t)j*227 + 35 + d] : 0.f;
    }
    if (threadIdx.x < 128) {
      int j = j0 + threadIdx.x;
      snorm[threadIdx.x] = (j < jend) ? nr[j] : 1e30f;
    }
    __syncthreads();
    for (int jj = 0; jj < 128; jj++) {
      float a0=0.f,a1=0.f,a2=0.f,a3=0.f;
#pragma unroll
      for (int q=0;q<16;q++){
        float4 s = sj[jj][q];
        a0 += fr[q].x*s.x; a1 += fr[q].y*s.y; a2 += fr[q].z*s.z; a3 += fr[q].w*s.w;
      }
      int j = j0 + jj;
      float v = 2.f*((a0+a1)+(a2+a3)) - ni - snorm[jj];
      if (j != i && v > tv4) {
        tv4 = v; tj4 = j;
        BUBBLE();
      }
    }
  }
  size_t base = ((size_t)part*N_PTS + i)*KNN_K;
  candv[base+0]=tv0; candv[base+1]=tv1; candv[base+2]=tv2; candv[base+3]=tv3; candv[base+4]=tv4;
  candi[base+0]=tj0; candi[base+1]=tj1; candi[base+2]=tj2; candi[base+3]=tj3; candi[base+4]=tj4;
}

__global__ void knn_merge_k(const float* __restrict__ candv, const int* __restrict__ candi,
                            int* __restrict__ out){
  int i = blockIdx.x*256 + threadIdx.x;
  if (i >= N_PTS) return;
  float tv0=-1e30f,tv1=-1e30f,tv2=-1e30f,tv3=-1e30f,tv4=-1e30f;
  int tj0=0,tj1=0,tj2=0,tj3=0,tj4=0;
  for (int p=0;p<JSPLIT;p++){
    size_t base = ((size_t)p*N_PTS + i)*KNN_K;
    for (int s=0;s<KNN_K;s++){
      float v = candv[base+s]; int j = candi[base+s];
      if (v > tv4){
        tv4 = v; tj4 = j;
        BUBBLE();
      }
    }
  }
  out[i*KNN_K+0]=tj0; out[i*KNN_K+1]=tj1; out[i*KNN_K+2]=tj2; out[i*KNN_K+3]=tj3; out[i*KNN_K+4]=tj4;
}

__global__ __launch_bounds__(256) void head_k(const float* __restrict__ h, const float* __restrict__ wf,
                                              const float* __restrict__ bfp, float* __restrict__ out, int rows){
  int lane = threadIdx.x & 63;
  int wid  = threadIdx.x >> 6;
  int r = blockIdx.x*4 + wid;
  if (r >= rows) return;
  float acc = h[(size_t)r*128 + lane]      * wf[lane]
            + h[(size_t)r*128 + 64 + lane] * wf[64+lane];
  for (int off=32; off>0; off>>=1) acc += __shfl_down(acc, off, 64);
  if (lane==0) out[r] = acc + bfp[0];
}

__global__ __launch_bounds__(64) void softgather_k(const float* __restrict__ logits,
                                                   const int* __restrict__ up_idx,
                                                   const float* __restrict__ xf,
                                                   float* __restrict__ z){
  __shared__ float lw[KUP]; __shared__ int li[KUP];
  int m = blockIdx.x;
  int tid = threadIdx.x;
  if (tid < KUP){ lw[tid] = logits[(size_t)m*KUP + tid]; li[tid] = up_idx[(size_t)m*KUP + tid]; }
  __syncthreads();
  float mx = -1e30f;
  for (int k=0;k<KUP;k++) mx = fmaxf(mx, lw[k]);
  __syncthreads();
  if (tid < KUP) lw[tid] = expf(lw[tid]-mx);
  __syncthreads();
  float s = 0.f;
  for (int k=0;k<KUP;k++) s += lw[k];
  float inv = 1.f/s;
  for (int c = tid; c < 227; c += 64){
    float acc = 0.f;
    for (int k=0;k<KUP;k++) acc += lw[k] * xf[(size_t)li[k]*227 + c];
    z[(size_t)m*227 + c] = acc*inv;
  }
}

__global__ void final_k(const float* __restrict__ h, const float* __restrict__ wf,
                        const float* __restrict__ bfp, void* __restrict__ out,
                        int r0, int rows, const int* __restrict__ flag){
  int m = blockIdx.x*256 + threadIdx.x;
  if (m >= rows) return;
  float hv[16];
#pragma unroll
  for (int d=0;d<16;d++) hv[d] = h[(size_t)m*16 + d];
#pragma unroll
  for (int o=0;o<3;o++){
    float acc = 0.f;
#pragma unroll
    for (int d=0;d<16;d++) acc += hv[d]*wf[o*16+d];
    float v = acc + bfp[o];
    if (!(fabsf(v) < 1e30f)) v = 777.0f;   // NaN/inf canary
    size_t oi = (size_t)(r0+m)*3+o;
    if (flag[0]) ((bf16*)out)[oi] = __float2bfloat16(v);
    else         ((float*)out)[oi] = v;
  }
}

// ---------------------------------------------------------------------------
extern "C" void kernel_launch(void* const* d_in, const int* in_sizes, int n_in,
                              void* d_out, int out_size, void* d_ws, size_t ws_size,
                              hipStream_t stream) {
  const int *idx0  = (const int*)d_in[3];
  const int *upidx = (const int*)d_in[37];

  // ---- workspace layout (floats) ----
  float* ws = (float*)d_ws;
  float* x_feat = ws;                     // [N,227]
  float* f1b    = ws + 3602944;           // [N,128]
  float* pmax   = ws + 5634560;
  float* psum   = ws + 5667328;
  float* fmaxv  = ws + 5700096;
  float* favgv  = ws + 5700224;
  int*   flag   = (int*)(ws + 5700352);
  int*   idx1   = (int*)(ws + 5700368);   // N*5
  float* nrm    = ws + 5779728;           // N
  float* logits = ws + 5795600;           // UP_ROWS
  float* wcvt   = ws + 6508352;           // 706,020 fp32 weights
  float* S      = ws + 7214400;           // scratch arena, peak 9,662,464

  const size_t NEED = (size_t)(7214400 + 9662464) * 4;  // ~64.4 MiB
  if (ws_size < NEED) {
    fillmark_k<<<CDIV(out_size,256),256,0,stream>>>((bf16*)d_out, out_size);
    return;
  }

  // ---- dtype flag + weight conversion to fp32 ----
  flag_k<<<1,64,0,stream>>>((const unsigned*)d_in[2], flag);
  float* wc = wcvt;
  auto CVT = [&](int i, int n)->const float* {
    float* dst = wc; wc += n;
    cvtw_k<<<CDIV(n,256),256,0,stream>>>(d_in[i], dst, n, flag);
    return dst;
  };
  const float *E0W1=CVT(4,8960),  *E0S1=CVT(5,128),  *E0H1=CVT(6,128),
              *E0W2=CVT(7,8192),  *E0B2=CVT(8,64);
  const float *F0W1=CVT(9,43584), *F0S1=CVT(10,192), *F0H1=CVT(11,192),
              *F0W2=CVT(12,24576),*F0S2=CVT(13,128), *F0H2=CVT(14,128),
              *F0W3=CVT(15,8192), *F0S3=CVT(16,64),  *F0H3=CVT(17,64),
              *F0W4=CVT(18,4096), *F0B4=CVT(19,64);
  const float *E1W1=CVT(20,32768),*E1S1=CVT(21,256), *E1H1=CVT(22,256),
              *E1W2=CVT(23,32768),*E1B2=CVT(24,128);
  const float *F1W1=CVT(25,172032),*F1S1=CVT(26,384),*F1H1=CVT(27,384),
              *F1W2=CVT(28,98304),*F1S2=CVT(29,256), *F1H2=CVT(30,256),
              *F1W3=CVT(31,32768),*F1S3=CVT(32,128), *F1H3=CVT(33,128),
              *F1W4=CVT(34,16384),*F1B4=CVT(35,128);
  const float *UPW0=CVT(38,896),  *UPS0=CVT(39,128), *UPH0=CVT(40,128),
              *UPWR=CVT(41,114688),*UPSR=CVT(42,896),*UPHR=CVT(43,896),
              *UPWF=CVT(44,128),  *UPBF=CVT(45,1);
  const float *DW0=CVT(46,58112), *DB0=CVT(47,256),
              *DW1=CVT(48,32768), *DB1=CVT(49,128),
              *DW2=CVT(50,8192),  *DB2=CVT(51,64),
              *DW3=CVT(52,2048),  *DB3=CVT(53,32),
              *DW4=CVT(54,512),   *DB4=CVT(55,16),
              *DWF=CVT(56,48),    *DBF=CVT(57,3);

  const float invN = 1.f/(float)N_PTS;
  const int CHP = 3072;    // edge-phase point chunk
  const int CHN = 8192;    // fc-phase row chunk
  const int CHS = 32768;   // SIREN row chunk
  const int CHD = 4096;    // decoder row chunk

  featin_k<<<CDIV(N_PTS*35,256),256,0,stream>>>(d_in[1], d_in[2], x_feat, flag);

  // ---- phase 1: emb block 0
  for (int n0 = 0; n0 < N_PTS; n0 += CHP) {
    int np = N_PTS - n0; if (np > CHP) np = CHP;
    int ne = np * KNN_K;
    float* eA = S;
    float* eB = S + 1075200;
    gather_e_k<<<CDIV(ne*70,256),256,0,stream>>>(x_feat, 0, 35, idx0, eA, n0, np);
    gemm_k<0,1><<<dim3(CDIV(ne,64),2),256,0,stream>>>(eA,70, E0W1,70, E0S1,E0H1,0.f, eB,128, ne,128,70);
    gemm_k<1,0><<<dim3(CDIV(ne,64),1),256,0,stream>>>(eB,128, E0W2,128, nullptr,E0B2,0.f, eA,64, ne,64,128);
    kmax_k<<<CDIV(np*64,256),256,0,stream>>>(eA, 64, f1b, n0, np);
  }
  reduce1_k<64><<<256,256,0,stream>>>(f1b, N_PTS, pmax, psum);
  reduce2_k<64><<<1,64,0,stream>>>(pmax, psum, 256, invN, fmaxv, favgv);
  for (int n0 = 0; n0 < N_PTS; n0 += CHN) {
    int np = N_PTS - n0; if (np > CHN) np = CHN;
    float* h  = S;
    float* a1 = S + 1859584;
    int gx = CDIV(np,64);
    concat_k<<<CDIV(np*227,256),256,0,stream>>>(x_feat,0,35, f1b,64, fmaxv,favgv, h, n0, np);
    gemm_k<0,1><<<dim3(gx,3),256,0,stream>>>(h,227,  F0W1,227, F0S1,F0H1,0.f, a1,192, np,192,227);
    gemm_k<0,1><<<dim3(gx,2),256,0,stream>>>(a1,192, F0W2,192, F0S2,F0H2,0.f, h,128,  np,128,192);
    gemm_k<0,1><<<dim3(gx,1),256,0,stream>>>(h,128,  F0W3,128, F0S3,F0H3,0.f, a1,64,  np,64,128);
    gemm_k<1,0><<<dim3(gx,1),256,0,stream>>>(a1,64,  F0W4,64,  nullptr,F0B4,0.f, x_feat+(size_t)n0*227+35,227, np,64,64);
  }

  // ---- phase 2: dynamic KNN
  norms_k<<<CDIV(N_PTS,256),256,0,stream>>>(x_feat, nrm);
  {
    float* candv = S;
    int*   candi = (int*)(S + 634880);
    knn_k<<<dim3(N_PTS/256, JSPLIT),256,0,stream>>>(x_feat, nrm, candv, candi);
    knn_merge_k<<<CDIV(N_PTS,256),256,0,stream>>>(candv, candi, idx1);
  }

  // ---- phase 3: emb block 1
  for (int n0 = 0; n0 < N_PTS; n0 += CHP) {
    int np = N_PTS - n0; if (np > CHP) np = CHP;
    int ne = np * KNN_K;
    float* eA = S;
    float* eB = S + 1966080;
    gather_e_k<<<CDIV(ne*128,256),256,0,stream>>>(x_feat, 35, 64, idx1, eA, n0, np);
    gemm_k<0,1><<<dim3(CDIV(ne,64),4),256,0,stream>>>(eA,128, E1W1,128, E1S1,E1H1,0.f, eB,256, ne,256,128);
    gemm_k<1,0><<<dim3(CDIV(ne,64),2),256,0,stream>>>(eB,256, E1W2,256, nullptr,E1B2,0.f, eA,128, ne,128,256);
    kmax_k<<<CDIV(np*128,256),256,0,stream>>>(eA, 128, f1b, n0, np);
  }
  reduce1_k<128><<<256,256,0,stream>>>(f1b, N_PTS, pmax, psum);
  reduce2_k<128><<<1,128,0,stream>>>(pmax, psum, 256, invN, fmaxv, favgv);
  for (int n0 = 0; n0 < N_PTS; n0 += CHN) {
    int np = N_PTS - n0; if (np > CHN) np = CHN;
    float* h  = S;
    float* a1 = S + 3670016;
    int gx = CDIV(np,64);
    concat_k<<<CDIV(np*448,256),256,0,stream>>>(x_feat,35,64, f1b,128, fmaxv,favgv, h, n0, np);
    gemm_k<0,1><<<dim3(gx,6),256,0,stream>>>(h,448,  F1W1,448, F1S1,F1H1,0.f, a1,384, np,384,448);
    gemm_k<0,1><<<dim3(gx,4),256,0,stream>>>(a1,384, F1W2,384, F1S2,F1H2,0.f, h,256,  np,256,384);
    gemm_k<0,1><<<dim3(gx,2),256,0,stream>>>(h,256,  F1W3,256, F1S3,F1H3,0.f, a1,128, np,128,256);
    gemm_k<1,0><<<dim3(gx,2),256,0,stream>>>(a1,128, F1W4,128, nullptr,F1B4,0.f, x_feat+(size_t)n0*227+99,227, np,128,128);
  }

  // ---- phase 4: upscale SIREN stack -> logits; softmax gather -> z
  {
    float* ping = S;
    float* pong = S + 4194304;
    for (int off = 0; off < UP_ROWS; off += CHS) {
      int rows = UP_ROWS - off; if (rows > CHS) rows = CHS;
      int gb = CDIV(rows,64);
      gemm_ak<0,2><<<dim3(gb,2),256,0,stream>>>(d_in[36],7, off, UPW0,7, UPS0,UPH0,0.f,
                                                ping,128, rows,128,7, flag);
      float* cur = ping; float* nxt = pong;
      for (int l=0;l<7;l++){
        gemm_k<0,2><<<dim3(gb,2),256,0,stream>>>(cur,128, UPWR + (size_t)l*16384, 128,
                                                 UPSR + l*128, UPHR + l*128, 0.f, nxt,128, rows,128,128);
        float* t=cur; cur=nxt; nxt=t;
      }
      head_k<<<CDIV(rows,4),256,0,stream>>>(cur, UPWF, UPBF, logits + off, rows);
    }
  }
  float* zbuf = S;                 // [M,227]
  softgather_k<<<M_PTS,64,0,stream>>>(logits, upidx, x_feat, zbuf);

  // ---- phase 5: SIREN decoder
  {
    float* A  = S + 8089600;            // [CHD,256]
    float* Bb = S + 8089600 + 1048576;  // [CHD,128]
    for (int r0 = 0; r0 < M_PTS; r0 += CHD) {
      int rows = M_PTS - r0; if (rows > CHD) rows = CHD;
      int gx = CDIV(rows,64);
      gemm_k<2,2><<<dim3(gx,4),256,0,stream>>>(zbuf + (size_t)r0*227,227, DW0,227, nullptr,DB0,30.f, A,256,  rows,256,227);
      gemm_k<1,2><<<dim3(gx,2),256,0,stream>>>(A,256,  DW1,256, nullptr,DB1,0.f, Bb,128, rows,128,256);
      gemm_k<1,2><<<dim3(gx,1),256,0,stream>>>(Bb,128, DW2,128, nullptr,DB2,0.f, A,64,   rows,64,128);
      gemm_k<1,2><<<dim3(gx,1),256,0,stream>>>(A,64,   DW3,64,  nullptr,DB3,0.f, Bb,32,  rows,32,64);
      gemm_k<1,2><<<dim3(gx,1),256,0,stream>>>(Bb,32,  DW4,32,  nullptr,DB4,0.f, A,16,   rows,16,32);
      final_k<<<CDIV(rows,256),256,0,stream>>>(A, DWF, DBF, d_out, r0, rows, flag);
    }
  }
}

// Round 4
// 4741.587 us; speedup vs baseline: 1.6338x; 1.6338x over previous
//
#include <hip/hip_runtime.h>
#include <hip/hip_bf16.h>
#include <math.h>

#define N_PTS 15872
#define M_PTS 35637
#define KNN_K 5
#define KUP   20
#define JSPLIT 8
#define UP_ROWS (M_PTS * KUP)   // 712740
#define CDIV(a,b) (((a)+(b)-1)/(b))

typedef __hip_bfloat16 bf16;
typedef unsigned int uint;
__device__ __forceinline__ float b2f(bf16 x){ return __bfloat162float(x); }

// round-to-nearest-even fp32 -> bf16 bit pattern (finite inputs)
__device__ __forceinline__ uint f2bf_bits(float x){
  uint u = __float_as_uint(x);
  return (u + 0x7FFFu + ((u>>16)&1u)) >> 16;
}

typedef __attribute__((ext_vector_type(8))) short bf16x8;
typedef __attribute__((ext_vector_type(16))) float f32x16;
union FragAB { bf16x8 v; uint u[4]; };
union Acc16  { f32x16 v; float f[16]; };

// ---------------------------------------------------------------------------
__global__ void flag_k(const uint* __restrict__ pos_raw, int* __restrict__ flag){
  if (threadIdx.x == 0 && blockIdx.x == 0)
    flag[0] = (pos_raw[0] == 0x3F800000u) ? 1 : 0;
}

__global__ void cvtw_k(const void* __restrict__ src, float* __restrict__ dst, int n,
                       const int* __restrict__ flag){
  int i = blockIdx.x*256 + threadIdx.x;
  if (i >= n) return;
  if (flag[0]) dst[i] = b2f(((const bf16*)src)[i]);
  else         dst[i] = ((const float*)src)[i];
}

// split fp32 -> packed (hi_bf16<<16)|lo_bf16
__global__ void packw_k(const float* __restrict__ w, uint* __restrict__ out, int n){
  int i = blockIdx.x*256 + threadIdx.x;
  if (i >= n) return;
  float x = w[i];
  uint hb = f2bf_bits(x);
  float hfv = __uint_as_float(hb<<16);
  uint lb = f2bf_bits(x - hfv);
  out[i] = (hb<<16) | lb;
}

__global__ void fillmark_k(bf16* __restrict__ out, int n){
  int i = blockIdx.x*256 + threadIdx.x;
  if (i < n) out[i] = __float2bfloat16(12345.0f);
}

// ---------------------------------------------------------------------------
// Generic fused GEMM (fp32):  C[m,n] = ACT( EPI( sum_k A[m,k]*W[n,k] ) )
// EPI 0: v*scale[n]+shift[n]   EPI 1: v+shift[n]   EPI 2: (v+shift[n])*gmul
// ACT 0: none   ACT 1: lrelu(0.2)   ACT 2: sin
// ---------------------------------------------------------------------------
template<int EPI, int ACT>
__global__ __launch_bounds__(256) void gemm_k(
    const float* __restrict__ A, int lda,
    const float* __restrict__ W, int ldw,
    const float* __restrict__ scale, const float* __restrict__ shift,
    float gmul, float* __restrict__ C, int ldc,
    int M, int Nout, int K)
{
  __shared__ __align__(16) float As[16][64];
  __shared__ __align__(16) float Ws[16][64];
  const int tid = threadIdx.x;
  const int tx = tid & 15, ty = tid >> 4;
  const int bm = blockIdx.x * 64, bn = blockIdx.y * 64;
  const int ar = tid >> 2, ak = (tid & 3) * 4;
  float acc[4][4] = {};
  for (int k0 = 0; k0 < K; k0 += 16) {
    float a0=0.f,a1=0.f,a2=0.f,a3=0.f;
    int grow = bm + ar;
    if (grow < M) {
      const float* ap = A + (size_t)grow * lda + (k0 + ak);
      int rem = K - (k0 + ak);
      if (rem >= 4) { a0=ap[0]; a1=ap[1]; a2=ap[2]; a3=ap[3]; }
      else { if(rem>0)a0=ap[0]; if(rem>1)a1=ap[1]; if(rem>2)a2=ap[2]; }
    }
    float w0=0.f,w1=0.f,w2=0.f,w3=0.f;
    int gn = bn + ar;
    if (gn < Nout) {
      const float* wp = W + (size_t)gn * ldw + (k0 + ak);
      int rem = K - (k0 + ak);
      if (rem >= 4) { w0=wp[0]; w1=wp[1]; w2=wp[2]; w3=wp[3]; }
      else { if(rem>0)w0=wp[0]; if(rem>1)w1=wp[1]; if(rem>2)w2=wp[2]; }
    }
    __syncthreads();
    As[ak+0][ar]=a0; As[ak+1][ar]=a1; As[ak+2][ar]=a2; As[ak+3][ar]=a3;
    Ws[ak+0][ar]=w0; Ws[ak+1][ar]=w1; Ws[ak+2][ar]=w2; Ws[ak+3][ar]=w3;
    __syncthreads();
#pragma unroll
    for (int kk = 0; kk < 16; kk++) {
      float4 av = *reinterpret_cast<const float4*>(&As[kk][ty*4]);
      float4 wv = *reinterpret_cast<const float4*>(&Ws[kk][tx*4]);
      float aa[4] = {av.x,av.y,av.z,av.w};
      float ww[4] = {wv.x,wv.y,wv.z,wv.w};
#pragma unroll
      for (int i=0;i<4;i++)
#pragma unroll
        for (int j=0;j<4;j++) acc[i][j] += aa[i]*ww[j];
    }
  }
#pragma unroll
  for (int i=0;i<4;i++){
    int m = bm + ty*4 + i;
    if (m >= M) continue;
#pragma unroll
    for (int j=0;j<4;j++){
      int n = bn + tx*4 + j;
      if (n >= Nout) continue;
      float v = acc[i][j];
      if (EPI==0)      v = v * scale[n] + shift[n];
      else if (EPI==1) v = v + shift[n];
      else             v = (v + shift[n]) * gmul;
      if (ACT==1)      v = v > 0.f ? v : 0.2f*v;
      else if (ACT==2) v = sinf(v);
      C[(size_t)m*ldc + n] = v;
    }
  }
}

// ---------------------------------------------------------------------------
// Fused 8-layer SIREN upscale stack + head, split-bf16 MFMA.
// Block: 128 threads = 2 waves, each wave owns 32 rows. TM=64 rows/block.
// act LDS: [64 rows][132 u32] packed (hi_bf16<<16|lo_bf16).
// W LDS: quarter-staged [128 n][34 u32] packed.
// ---------------------------------------------------------------------------
__global__ __launch_bounds__(128) void siren_fused_k(
    const void* __restrict__ upin, const uint* __restrict__ wpack,
    const float* __restrict__ W0c, const float* __restrict__ S0c, const float* __restrict__ H0c,
    const float* __restrict__ SRc, const float* __restrict__ HRc,
    const float* __restrict__ WFc, const float* __restrict__ BFc,
    float* __restrict__ logits, const int* __restrict__ flag)
{
  __shared__ __align__(16) uint Wq[128*34];      // 17408 B
  __shared__ __align__(16) uint act[64*132];     // 33792 B
  __shared__ float sh0[128], sh1[128];
  __shared__ float w0s[128*9];                   // stride 9: conflict-free
  __shared__ float intile[64*8];
  __shared__ float wfs[128];
  __shared__ float bfs;

  const int tid = threadIdx.x;
  const int lane = tid & 63;
  const int wv = tid >> 6;            // 0..1
  const int np = lane & 31;           // n' (B cols / D cols) or m' (A rows)
  const int hb2 = lane >> 5;          // 0..1 (k-half of frag)
  const long rowbase = (long)blockIdx.x * 64;
  const int isbf = flag[0];

  // ---- stage layer-0 weights, sh, wf, input tile ----
  for (int e = tid; e < 128*7; e += 128) w0s[(e/7)*9 + (e%7)] = W0c[e];
  if (tid < 128) { sh0[tid] = S0c[tid]; sh1[tid] = H0c[tid]; wfs[tid] = WFc[tid]; }
  if (tid == 0) bfs = BFc[0];
  for (int e = tid; e < 64*7; e += 128) {
    int r = e/7, k = e%7;
    long gr = rowbase + r;
    float v = 0.f;
    if (gr < UP_ROWS)
      v = isbf ? b2f(((const bf16*)upin)[gr*7+k]) : ((const float*)upin)[gr*7+k];
    intile[r*8+k] = v;
  }
  __syncthreads();

  // ---- layer 0 (7 -> 128): write act rows wv*32..wv*32+31 in D-layout slots
  for (int t = 0; t < 4; t++) {
    int c = t*32 + np;
    float s = sh0[c], b = sh1[c];
#pragma unroll
    for (int reg = 0; reg < 16; reg++) {
      int r = wv*32 + (reg&3) + 8*(reg>>2) + 4*hb2;
      float a = 0.f;
#pragma unroll
      for (int k = 0; k < 7; k++) a += intile[r*8+k]*w0s[c*9+k];
      float x = __sinf(a*s + b);
      uint hbi = f2bf_bits(x);
      uint lbi = f2bf_bits(x - __uint_as_float(hbi<<16));
      act[r*132 + c] = (hbi<<16) | lbi;
    }
  }

  // ---- layers 1..7 (128 -> 128), split-bf16 MFMA ----
  for (int l = 0; l < 7; l++) {
    Acc16 acc[4];
#pragma unroll
    for (int t=0;t<4;t++)
#pragma unroll
      for (int i=0;i<16;i++) acc[t].f[i] = 0.f;

    for (int Q = 0; Q < 4; Q++) {
      __syncthreads();
      // stage W quarter: Wq[n*34+kk] = wpack[l*16384 + n*128 + Q*32 + kk]
      for (int e = tid*4; e < 128*32; e += 128*4) {
        int n = e >> 5, kk = e & 31;
        uint4 src = *(const uint4*)&wpack[l*16384 + n*128 + Q*32 + kk];
        uint* d = &Wq[n*34 + kk];
        d[0]=src.x; d[1]=src.y; d[2]=src.z; d[3]=src.w;
      }
      if (Q==0 && tid < 128) { sh0[tid] = SRc[l*128+tid]; sh1[tid] = HRc[l*128+tid]; }
      __syncthreads();
#pragma unroll
      for (int ks = 0; ks < 2; ks++) {
        // A-frag: row = wv*32+np, k = Q*32 + ks*16 + hb2*8 + j
        uint au[8];
        const uint* ap = &act[(wv*32+np)*132 + Q*32 + ks*16 + hb2*8];
        *(uint4*)&au[0] = *(const uint4*)ap;
        *(uint4*)&au[4] = *(const uint4*)(ap+4);
        FragAB ahi, alo;
#pragma unroll
        for (int p=0;p<4;p++){
          ahi.u[p] = (au[2*p]>>16)      | (au[2*p+1] & 0xFFFF0000u);
          alo.u[p] = (au[2*p]&0xFFFFu)  | (au[2*p+1]<<16);
        }
#pragma unroll
        for (int t=0;t<4;t++){
          uint bu[8];
          const uint* bp = &Wq[(t*32+np)*34 + ks*16 + hb2*8];
          *(uint2*)&bu[0] = *(const uint2*)(bp+0);
          *(uint2*)&bu[2] = *(const uint2*)(bp+2);
          *(uint2*)&bu[4] = *(const uint2*)(bp+4);
          *(uint2*)&bu[6] = *(const uint2*)(bp+6);
          FragAB bhi, blo;
#pragma unroll
          for (int p=0;p<4;p++){
            bhi.u[p] = (bu[2*p]>>16)     | (bu[2*p+1] & 0xFFFF0000u);
            blo.u[p] = (bu[2*p]&0xFFFFu) | (bu[2*p+1]<<16);
          }
          acc[t].v = __builtin_amdgcn_mfma_f32_32x32x16_bf16(ahi.v, bhi.v, acc[t].v, 0,0,0);
          acc[t].v = __builtin_amdgcn_mfma_f32_32x32x16_bf16(alo.v, bhi.v, acc[t].v, 0,0,0);
          acc[t].v = __builtin_amdgcn_mfma_f32_32x32x16_bf16(ahi.v, blo.v, acc[t].v, 0,0,0);
        }
      }
    }
    // epilogue: scale/shift + sin + split-pack back to act (wave-private rows)
#pragma unroll
    for (int t=0;t<4;t++){
      int c = t*32 + np;
      float s = sh0[c], b = sh1[c];
#pragma unroll
      for (int reg=0;reg<16;reg++){
        int r = wv*32 + (reg&3) + 8*(reg>>2) + 4*hb2;
        float x = __sinf(acc[t].f[reg]*s + b);
        uint hbi = f2bf_bits(x);
        uint lbi = f2bf_bits(x - __uint_as_float(hbi<<16));
        act[r*132 + c] = (hbi<<16) | lbi;
      }
    }
  }

  // ---- head (128 -> 1): 2 lanes per row, k-halves
  {
    int r = wv*32 + np;
    const uint* ap = &act[r*132 + hb2*64];
    float a = 0.f;
#pragma unroll
    for (int k = 0; k < 64; k += 4) {
      uint4 u = *(const uint4*)(ap + k);
      float x0 = __uint_as_float(u.x & 0xFFFF0000u) + __uint_as_float(u.x<<16);
      float x1 = __uint_as_float(u.y & 0xFFFF0000u) + __uint_as_float(u.y<<16);
      float x2 = __uint_as_float(u.z & 0xFFFF0000u) + __uint_as_float(u.z<<16);
      float x3 = __uint_as_float(u.w & 0xFFFF0000u) + __uint_as_float(u.w<<16);
      a += x0*wfs[hb2*64+k] + x1*wfs[hb2*64+k+1] + x2*wfs[hb2*64+k+2] + x3*wfs[hb2*64+k+3];
    }
    a += __shfl_xor(a, 32, 64);
    long gr = rowbase + r;
    if (hb2 == 0 && gr < UP_ROWS) logits[gr] = a + bfs;
  }
}

// ---------------------------------------------------------------------------
__global__ void featin_k(const void* __restrict__ ldx, const void* __restrict__ pos,
                         float* __restrict__ xf, const int* __restrict__ flag){
  int i = blockIdx.x*256 + threadIdx.x;
  if (i >= N_PTS*35) return;
  int n = i / 35, c = i % 35;
  float v;
  if (flag[0]) {
    v = (c < 3) ? b2f(((const bf16*)ldx)[n*3+c]) : b2f(((const bf16*)pos)[n*32 + (c-3)]);
  } else {
    v = (c < 3) ? ((const float*)ldx)[n*3+c] : ((const float*)pos)[n*32 + (c-3)];
  }
  xf[(size_t)n*227 + c] = v;
}

__global__ void gather_e_k(const float* __restrict__ xf, int coff, int CIN,
                           const int* __restrict__ idx, float* __restrict__ e,
                           int n0, int np){
  int W2 = 2*CIN;
  int i = blockIdx.x*256 + threadIdx.x;
  if (i >= np*KNN_K*W2) return;
  int c = i % W2; int ek = i / W2;
  int nl = ek / KNN_K, k = ek % KNN_K;
  int n = n0 + nl;
  int j = idx[n*KNN_K + k];
  float out;
  if (c < CIN) out = xf[(size_t)j*227 + coff + c] - xf[(size_t)n*227 + coff + c];
  else         out = xf[(size_t)n*227 + coff + (c-CIN)];
  e[(size_t)ek*W2 + c] = out;
}

__global__ void kmax_k(const float* __restrict__ e2, int C, float* __restrict__ f1,
                       int n0, int np){
  int i = blockIdx.x*256 + threadIdx.x;
  if (i >= np*C) return;
  int nl = i / C, c = i % C;
  float v = -1e30f;
  for (int k=0;k<KNN_K;k++) v = fmaxf(v, e2[((size_t)nl*KNN_K+k)*C + c]);
  f1[(size_t)(n0+nl)*C + c] = v;
}

template<int C>
__global__ __launch_bounds__(256) void reduce1_k(const float* __restrict__ X, int n,
                                                 float* __restrict__ pmax, float* __restrict__ psum){
  const int tid = threadIdx.x;
  const int c = tid % C;
  const int r0 = tid / C;
  const int TPR = 256 / C;
  float vmax = -1e30f, vsum = 0.f;
  for (int row = blockIdx.x * TPR + r0; row < n; row += gridDim.x * TPR) {
    float v = X[(size_t)row * C + c];
    vmax = fmaxf(vmax, v); vsum += v;
  }
  __shared__ float smax[256], ssum[256];
  smax[tid]=vmax; ssum[tid]=vsum;
  __syncthreads();
  if (tid < C) {
    for (int q=1;q<TPR;q++){ vmax=fmaxf(vmax, smax[q*C+c]); vsum += ssum[q*C+c]; }
    pmax[blockIdx.x*C + c] = vmax; psum[blockIdx.x*C + c] = vsum;
  }
}

template<int C>
__global__ void reduce2_k(const float* __restrict__ pmax, const float* __restrict__ psum,
                          int nblk, float invn, float* __restrict__ fmaxo, float* __restrict__ favgo){
  int c = threadIdx.x; if (c >= C) return;
  float vmax=-1e30f, vsum=0.f;
  for (int b=0;b<nblk;b++){ vmax=fmaxf(vmax,pmax[b*C+c]); vsum+=psum[b*C+c]; }
  fmaxo[c]=vmax; favgo[c]=vsum*invn;
}

__global__ void concat_k(const float* __restrict__ xf, int coff, int CF,
                         const float* __restrict__ f1, int C,
                         const float* __restrict__ fmax, const float* __restrict__ favg,
                         float* __restrict__ h, int n0, int np){
  int W = CF + 3*C;
  int i = blockIdx.x*256 + threadIdx.x;
  if (i >= np*W) return;
  int nl = i / W, c = i % W;
  int n = n0 + nl;
  float v;
  if (c < CF)          v = xf[(size_t)n*227 + coff + c];
  else if (c < CF+C)   v = f1[(size_t)n*C + (c-CF)];
  else if (c < CF+2*C) v = fmax[c-CF-C];
  else                 v = favg[c-CF-2*C];
  h[(size_t)nl*W + c] = v;
}

__global__ void norms_k(const float* __restrict__ xf, float* __restrict__ nr){
  int n = blockIdx.x*256 + threadIdx.x;
  if (n >= N_PTS) return;
  const float* p = xf + (size_t)n*227 + 35;
  float s = 0.f;
  for (int d=0;d<64;d++) s += p[d]*p[d];
  nr[n] = s;
}

#define BUBBLE() \
  if (tv4 > tv3){ float tf=tv3; tv3=tv4; tv4=tf; int ti=tj3; tj3=tj4; tj4=ti; } \
  if (tv3 > tv2){ float tf=tv2; tv2=tv3; tv3=tf; int ti=tj2; tj2=tj3; tj3=ti; } \
  if (tv2 > tv1){ float tf=tv1; tv1=tv2; tv2=tf; int ti=tj1; tj1=tj2; tj2=ti; } \
  if (tv1 > tv0){ float tf=tv0; tv0=tv1; tv1=tf; int ti=tj0; tj0=tj1; tj1=ti; }

__global__ __launch_bounds__(256) void knn_k(const float* __restrict__ xf,
                                             const float* __restrict__ nr,
                                             float* __restrict__ candv, int* __restrict__ candi){
  __shared__ __align__(16) float4 sj[128][16];
  __shared__ float snorm[128];
  const int i = blockIdx.x*256 + threadIdx.x;
  const int part = blockIdx.y;
  const int jbeg = part * (N_PTS / JSPLIT);
  const int jend = jbeg + (N_PTS / JSPLIT);
  float4 fr[16];
  {
    const float* p = xf + (size_t)i*227 + 35;
#pragma unroll
    for (int q=0;q<16;q++) fr[q] = make_float4(p[4*q],p[4*q+1],p[4*q+2],p[4*q+3]);
  }
  const float ni = nr[i];
  float tv0=-1e30f,tv1=-1e30f,tv2=-1e30f,tv3=-1e30f,tv4=-1e30f;
  int tj0=0,tj1=0,tj2=0,tj3=0,tj4=0;
  for (int j0 = jbeg; j0 < jend; j0 += 128) {
    __syncthreads();
    for (int u = threadIdx.x; u < 128*64; u += 256) {
      int jj = u >> 6, d = u & 63;
      int j = j0 + jj;
      ((float*)sj)[u] = (j < jend) ? xf[(size_t)j*227 + 35 + d] : 0.f;
    }
    if (threadIdx.x < 128) {
      int j = j0 + threadIdx.x;
      snorm[threadIdx.x] = (j < jend) ? nr[j] : 1e30f;
    }
    __syncthreads();
    for (int jj = 0; jj < 128; jj++) {
      float a0=0.f,a1=0.f,a2=0.f,a3=0.f;
#pragma unroll
      for (int q=0;q<16;q++){
        float4 s = sj[jj][q];
        a0 += fr[q].x*s.x; a1 += fr[q].y*s.y; a2 += fr[q].z*s.z; a3 += fr[q].w*s.w;
      }
      int j = j0 + jj;
      float v = 2.f*((a0+a1)+(a2+a3)) - ni - snorm[jj];
      if (j != i && v > tv4) {
        tv4 = v; tj4 = j;
        BUBBLE();
      }
    }
  }
  size_t base = ((size_t)part*N_PTS + i)*KNN_K;
  candv[base+0]=tv0; candv[base+1]=tv1; candv[base+2]=tv2; candv[base+3]=tv3; candv[base+4]=tv4;
  candi[base+0]=tj0; candi[base+1]=tj1; candi[base+2]=tj2; candi[base+3]=tj3; candi[base+4]=tj4;
}

__global__ void knn_merge_k(const float* __restrict__ candv, const int* __restrict__ candi,
                            int* __restrict__ out){
  int i = blockIdx.x*256 + threadIdx.x;
  if (i >= N_PTS) return;
  float tv0=-1e30f,tv1=-1e30f,tv2=-1e30f,tv3=-1e30f,tv4=-1e30f;
  int tj0=0,tj1=0,tj2=0,tj3=0,tj4=0;
  for (int p=0;p<JSPLIT;p++){
    size_t base = ((size_t)p*N_PTS + i)*KNN_K;
    for (int s=0;s<KNN_K;s++){
      float v = candv[base+s]; int j = candi[base+s];
      if (v > tv4){
        tv4 = v; tj4 = j;
        BUBBLE();
      }
    }
  }
  out[i*KNN_K+0]=tj0; out[i*KNN_K+1]=tj1; out[i*KNN_K+2]=tj2; out[i*KNN_K+3]=tj3; out[i*KNN_K+4]=tj4;
}

__global__ __launch_bounds__(64) void softgather_k(const float* __restrict__ logits,
                                                   const int* __restrict__ up_idx,
                                                   const float* __restrict__ xf,
                                                   float* __restrict__ z){
  __shared__ float lw[KUP]; __shared__ int li[KUP];
  int m = blockIdx.x;
  int tid = threadIdx.x;
  if (tid < KUP){ lw[tid] = logits[(size_t)m*KUP + tid]; li[tid] = up_idx[(size_t)m*KUP + tid]; }
  __syncthreads();
  float mx = -1e30f;
  for (int k=0;k<KUP;k++) mx = fmaxf(mx, lw[k]);
  __syncthreads();
  if (tid < KUP) lw[tid] = expf(lw[tid]-mx);
  __syncthreads();
  float s = 0.f;
  for (int k=0;k<KUP;k++) s += lw[k];
  float inv = 1.f/s;
  for (int c = tid; c < 227; c += 64){
    float acc = 0.f;
    for (int k=0;k<KUP;k++) acc += lw[k] * xf[(size_t)li[k]*227 + c];
    z[(size_t)m*227 + c] = acc*inv;
  }
}

__global__ void final_k(const float* __restrict__ h, const float* __restrict__ wf,
                        const float* __restrict__ bfp, void* __restrict__ out,
                        int r0, int rows, const int* __restrict__ flag){
  int m = blockIdx.x*256 + threadIdx.x;
  if (m >= rows) return;
  float hv[16];
#pragma unroll
  for (int d=0;d<16;d++) hv[d] = h[(size_t)m*16 + d];
#pragma unroll
  for (int o=0;o<3;o++){
    float acc = 0.f;
#pragma unroll
    for (int d=0;d<16;d++) acc += hv[d]*wf[o*16+d];
    float v = acc + bfp[o];
    if (!(fabsf(v) < 1e30f)) v = 777.0f;   // NaN/inf canary
    size_t oi = (size_t)(r0+m)*3+o;
    if (flag[0]) ((bf16*)out)[oi] = __float2bfloat16(v);
    else         ((float*)out)[oi] = v;
  }
}

// ---------------------------------------------------------------------------
extern "C" void kernel_launch(void* const* d_in, const int* in_sizes, int n_in,
                              void* d_out, int out_size, void* d_ws, size_t ws_size,
                              hipStream_t stream) {
  const int *idx0  = (const int*)d_in[3];
  const int *upidx = (const int*)d_in[37];

  // ---- workspace layout (floats) ----
  float* ws = (float*)d_ws;
  float* x_feat = ws;                     // [N,227]
  float* f1b    = ws + 3602944;           // [N,128]
  float* pmax   = ws + 5634560;
  float* psum   = ws + 5667328;
  float* fmaxv  = ws + 5700096;
  float* favgv  = ws + 5700224;
  int*   flag   = (int*)(ws + 5700352);
  int*   idx1   = (int*)(ws + 5700368);   // N*5
  float* nrm    = ws + 5779728;           // N
  float* logits = ws + 5795600;           // UP_ROWS
  float* wcvt   = ws + 6508352;           // 706,020 fp32 weights
  float* S      = ws + 7214400;           // scratch arena
  uint*  wpack  = (uint*)(S + 9662464);   // 114688 u32 packed SIREN weights

  const size_t NEED = (size_t)(7214400 + 9662464 + 114688) * 4;  // ~68 MB (< confirmed 71 MB)
  if (ws_size < NEED) {
    fillmark_k<<<CDIV(out_size,256),256,0,stream>>>((bf16*)d_out, out_size);
    return;
  }

  // ---- dtype flag + weight conversion to fp32 ----
  flag_k<<<1,64,0,stream>>>((const uint*)d_in[2], flag);
  float* wc = wcvt;
  auto CVT = [&](int i, int n)->const float* {
    float* dst = wc; wc += n;
    cvtw_k<<<CDIV(n,256),256,0,stream>>>(d_in[i], dst, n, flag);
    return dst;
  };
  const float *E0W1=CVT(4,8960),  *E0S1=CVT(5,128),  *E0H1=CVT(6,128),
              *E0W2=CVT(7,8192),  *E0B2=CVT(8,64);
  const float *F0W1=CVT(9,43584), *F0S1=CVT(10,192), *F0H1=CVT(11,192),
              *F0W2=CVT(12,24576),*F0S2=CVT(13,128), *F0H2=CVT(14,128),
              *F0W3=CVT(15,8192), *F0S3=CVT(16,64),  *F0H3=CVT(17,64),
              *F0W4=CVT(18,4096), *F0B4=CVT(19,64);
  const float *E1W1=CVT(20,32768),*E1S1=CVT(21,256), *E1H1=CVT(22,256),
              *E1W2=CVT(23,32768),*E1B2=CVT(24,128);
  const float *F1W1=CVT(25,172032),*F1S1=CVT(26,384),*F1H1=CVT(27,384),
              *F1W2=CVT(28,98304),*F1S2=CVT(29,256), *F1H2=CVT(30,256),
              *F1W3=CVT(31,32768),*F1S3=CVT(32,128), *F1H3=CVT(33,128),
              *F1W4=CVT(34,16384),*F1B4=CVT(35,128);
  const float *UPW0=CVT(38,896),  *UPS0=CVT(39,128), *UPH0=CVT(40,128),
              *UPWR=CVT(41,114688),*UPSR=CVT(42,896),*UPHR=CVT(43,896),
              *UPWF=CVT(44,128),  *UPBF=CVT(45,1);
  const float *DW0=CVT(46,58112), *DB0=CVT(47,256),
              *DW1=CVT(48,32768), *DB1=CVT(49,128),
              *DW2=CVT(50,8192),  *DB2=CVT(51,64),
              *DW3=CVT(52,2048),  *DB3=CVT(53,32),
              *DW4=CVT(54,512),   *DB4=CVT(55,16),
              *DWF=CVT(56,48),    *DBF=CVT(57,3);

  // pack SIREN 128x128 weights to split-bf16
  packw_k<<<CDIV(114688,256),256,0,stream>>>(UPWR, wpack, 114688);

  const float invN = 1.f/(float)N_PTS;
  const int CHP = 3072;    // edge-phase point chunk
  const int CHN = 8192;    // fc-phase row chunk
  const int CHD = 4096;    // decoder row chunk

  featin_k<<<CDIV(N_PTS*35,256),256,0,stream>>>(d_in[1], d_in[2], x_feat, flag);

  // ---- phase 1: emb block 0
  for (int n0 = 0; n0 < N_PTS; n0 += CHP) {
    int np = N_PTS - n0; if (np > CHP) np = CHP;
    int ne = np * KNN_K;
    float* eA = S;
    float* eB = S + 1075200;
    gather_e_k<<<CDIV(ne*70,256),256,0,stream>>>(x_feat, 0, 35, idx0, eA, n0, np);
    gemm_k<0,1><<<dim3(CDIV(ne,64),2),256,0,stream>>>(eA,70, E0W1,70, E0S1,E0H1,0.f, eB,128, ne,128,70);
    gemm_k<1,0><<<dim3(CDIV(ne,64),1),256,0,stream>>>(eB,128, E0W2,128, nullptr,E0B2,0.f, eA,64, ne,64,128);
    kmax_k<<<CDIV(np*64,256),256,0,stream>>>(eA, 64, f1b, n0, np);
  }
  reduce1_k<64><<<256,256,0,stream>>>(f1b, N_PTS, pmax, psum);
  reduce2_k<64><<<1,64,0,stream>>>(pmax, psum, 256, invN, fmaxv, favgv);
  for (int n0 = 0; n0 < N_PTS; n0 += CHN) {
    int np = N_PTS - n0; if (np > CHN) np = CHN;
    float* h  = S;
    float* a1 = S + 1859584;
    int gx = CDIV(np,64);
    concat_k<<<CDIV(np*227,256),256,0,stream>>>(x_feat,0,35, f1b,64, fmaxv,favgv, h, n0, np);
    gemm_k<0,1><<<dim3(gx,3),256,0,stream>>>(h,227,  F0W1,227, F0S1,F0H1,0.f, a1,192, np,192,227);
    gemm_k<0,1><<<dim3(gx,2),256,0,stream>>>(a1,192, F0W2,192, F0S2,F0H2,0.f, h,128,  np,128,192);
    gemm_k<0,1><<<dim3(gx,1),256,0,stream>>>(h,128,  F0W3,128, F0S3,F0H3,0.f, a1,64,  np,64,128);
    gemm_k<1,0><<<dim3(gx,1),256,0,stream>>>(a1,64,  F0W4,64,  nullptr,F0B4,0.f, x_feat+(size_t)n0*227+35,227, np,64,64);
  }

  // ---- phase 2: dynamic KNN
  norms_k<<<CDIV(N_PTS,256),256,0,stream>>>(x_feat, nrm);
  {
    float* candv = S;
    int*   candi = (int*)(S + 634880);
    knn_k<<<dim3(N_PTS/256, JSPLIT),256,0,stream>>>(x_feat, nrm, candv, candi);
    knn_merge_k<<<CDIV(N_PTS,256),256,0,stream>>>(candv, candi, idx1);
  }

  // ---- phase 3: emb block 1
  for (int n0 = 0; n0 < N_PTS; n0 += CHP) {
    int np = N_PTS - n0; if (np > CHP) np = CHP;
    int ne = np * KNN_K;
    float* eA = S;
    float* eB = S + 1966080;
    gather_e_k<<<CDIV(ne*128,256),256,0,stream>>>(x_feat, 35, 64, idx1, eA, n0, np);
    gemm_k<0,1><<<dim3(CDIV(ne,64),4),256,0,stream>>>(eA,128, E1W1,128, E1S1,E1H1,0.f, eB,256, ne,256,128);
    gemm_k<1,0><<<dim3(CDIV(ne,64),2),256,0,stream>>>(eB,256, E1W2,256, nullptr,E1B2,0.f, eA,128, ne,128,256);
    kmax_k<<<CDIV(np*128,256),256,0,stream>>>(eA, 128, f1b, n0, np);
  }
  reduce1_k<128><<<256,256,0,stream>>>(f1b, N_PTS, pmax, psum);
  reduce2_k<128><<<1,128,0,stream>>>(pmax, psum, 256, invN, fmaxv, favgv);
  for (int n0 = 0; n0 < N_PTS; n0 += CHN) {
    int np = N_PTS - n0; if (np > CHN) np = CHN;
    float* h  = S;
    float* a1 = S + 3670016;
    int gx = CDIV(np,64);
    concat_k<<<CDIV(np*448,256),256,0,stream>>>(x_feat,35,64, f1b,128, fmaxv,favgv, h, n0, np);
    gemm_k<0,1><<<dim3(gx,6),256,0,stream>>>(h,448,  F1W1,448, F1S1,F1H1,0.f, a1,384, np,384,448);
    gemm_k<0,1><<<dim3(gx,4),256,0,stream>>>(a1,384, F1W2,384, F1S2,F1H2,0.f, h,256,  np,256,384);
    gemm_k<0,1><<<dim3(gx,2),256,0,stream>>>(h,256,  F1W3,256, F1S3,F1H3,0.f, a1,128, np,128,256);
    gemm_k<1,0><<<dim3(gx,2),256,0,stream>>>(a1,128, F1W4,128, nullptr,F1B4,0.f, x_feat+(size_t)n0*227+99,227, np,128,128);
  }

  // ---- phase 4: fused split-bf16 MFMA SIREN -> logits; softmax gather -> z
  siren_fused_k<<<CDIV(UP_ROWS,64),128,0,stream>>>(
      d_in[36], wpack, UPW0, UPS0, UPH0, UPSR, UPHR, UPWF, UPBF, logits, flag);
  float* zbuf = S;                 // [M,227]
  softgather_k<<<M_PTS,64,0,stream>>>(logits, upidx, x_feat, zbuf);

  // ---- phase 5: SIREN decoder
  {
    float* A  = S + 8089600;            // [CHD,256]
    float* Bb = S + 8089600 + 1048576;  // [CHD,128]
    for (int r0 = 0; r0 < M_PTS; r0 += CHD) {
      int rows = M_PTS - r0; if (rows > CHD) rows = CHD;
      int gx = CDIV(rows,64);
      gemm_k<2,2><<<dim3(gx,4),256,0,stream>>>(zbuf + (size_t)r0*227,227, DW0,227, nullptr,DB0,30.f, A,256,  rows,256,227);
      gemm_k<1,2><<<dim3(gx,2),256,0,stream>>>(A,256,  DW1,256, nullptr,DB1,0.f, Bb,128, rows,128,256);
      gemm_k<1,2><<<dim3(gx,1),256,0,stream>>>(Bb,128, DW2,128, nullptr,DB2,0.f, A,64,   rows,64,128);
      gemm_k<1,2><<<dim3(gx,1),256,0,stream>>>(A,64,   DW3,64,  nullptr,DB3,0.f, Bb,32,  rows,32,64);
      gemm_k<1,2><<<dim3(gx,1),256,0,stream>>>(Bb,32,  DW4,32,  nullptr,DB4,0.f, A,16,   rows,16,32);
      final_k<<<CDIV(rows,256),256,0,stream>>>(A, DWF, DBF, d_out, r0, rows, flag);
    }
  }
}

// Round 5
// 3767.710 us; speedup vs baseline: 2.0561x; 1.2585x over previous
//
#include <hip/hip_runtime.h>
#include <hip/hip_bf16.h>
#include <math.h>

#define N_PTS 15872
#define M_PTS 35637
#define KNN_K 5
#define KUP   20
#define JSPLIT 8
#define UP_ROWS (M_PTS * KUP)   // 712740
#define CDIV(a,b) (((a)+(b)-1)/(b))

typedef __hip_bfloat16 bf16;
typedef unsigned int uint;
typedef unsigned short ushort_t;
__device__ __forceinline__ float b2f(bf16 x){ return __bfloat162float(x); }

// round-to-nearest-even fp32 -> bf16 bit pattern (finite inputs)
__device__ __forceinline__ uint f2bf_bits(float x){
  uint u = __float_as_uint(x);
  return (u + 0x7FFFu + ((u>>16)&1u)) >> 16;
}

typedef __attribute__((ext_vector_type(8))) short bf16x8;
typedef __attribute__((ext_vector_type(16))) float f32x16;
union FragAB { bf16x8 v; uint u[4]; };
union FragB  { bf16x8 v; uint4 q; };
union Acc16  { f32x16 v; float f[16]; };

// ---------------------------------------------------------------------------
__global__ void flag_k(const uint* __restrict__ pos_raw, int* __restrict__ flag){
  if (threadIdx.x == 0 && blockIdx.x == 0)
    flag[0] = (pos_raw[0] == 0x3F800000u) ? 1 : 0;
}

// one-shot conversion of ALL weight arrays (bf16 or fp32 per flag) to fp32
struct CvtTab { const void* src[52]; int start[52]; };
__global__ __launch_bounds__(256) void cvt_all_k(CvtTab tab, float* __restrict__ dst,
                                                 const int* __restrict__ flag, int total){
  int i = blockIdx.x*256 + threadIdx.x;
  if (i >= total) return;
  int s = 0;
#pragma unroll 1
  for (int k = 1; k < 52; k++) if (tab.start[k] <= i) s = k;
  int off = i - tab.start[s];
  float v = flag[0] ? b2f(((const bf16*)tab.src[s])[off]) : ((const float*)tab.src[s])[off];
  dst[i] = v;
}

// pack SIREN 128x128 weights into frag-major split-bf16 hi/lo planes.
// dst index i: j=i&7 (elem), lam=(i>>3)&63 (lane), fg=i>>9: t=fg&3, ks=(fg>>2)&1,
// Q=(fg>>3)&3, l=fg>>5. src: W[l][n=t*32+(lam&31)][k=Q*32+ks*16+(lam>>5)*8+j]
__global__ void packfrag_k(const float* __restrict__ w, ushort_t* __restrict__ whi,
                           ushort_t* __restrict__ wlo, int n){
  int i = blockIdx.x*256 + threadIdx.x;
  if (i >= n) return;
  int j = i & 7;
  int lam = (i >> 3) & 63;
  int fg = i >> 9;
  int t = fg & 3, ks = (fg >> 2) & 1, Q = (fg >> 3) & 3, l = fg >> 5;
  int nn = t*32 + (lam & 31);
  int kk = Q*32 + ks*16 + (lam >> 5)*8 + j;
  float x = w[l*16384 + nn*128 + kk];
  uint hb = f2bf_bits(x);
  float hf = __uint_as_float(hb << 16);
  uint lb = f2bf_bits(x - hf);
  whi[i] = (ushort_t)hb;
  wlo[i] = (ushort_t)lb;
}

__global__ void fillmark_k(bf16* __restrict__ out, int n){
  int i = blockIdx.x*256 + threadIdx.x;
  if (i < n) out[i] = __float2bfloat16(12345.0f);
}

// ---------------------------------------------------------------------------
// Generic fused GEMM (fp32):  C[m,n] = ACT( EPI( sum_k A[m,k]*W[n,k] ) )
// EPI 0: v*scale[n]+shift[n]   EPI 1: v+shift[n]   EPI 2: (v+shift[n])*gmul
// ACT 0: none   ACT 1: lrelu(0.2)   ACT 2: sin
// ---------------------------------------------------------------------------
template<int EPI, int ACT>
__global__ __launch_bounds__(256) void gemm_k(
    const float* __restrict__ A, int lda,
    const float* __restrict__ W, int ldw,
    const float* __restrict__ scale, const float* __restrict__ shift,
    float gmul, float* __restrict__ C, int ldc,
    int M, int Nout, int K)
{
  __shared__ __align__(16) float As[16][64];
  __shared__ __align__(16) float Ws[16][64];
  const int tid = threadIdx.x;
  const int tx = tid & 15, ty = tid >> 4;
  const int bm = blockIdx.x * 64, bn = blockIdx.y * 64;
  const int ar = tid >> 2, ak = (tid & 3) * 4;
  float acc[4][4] = {};
  for (int k0 = 0; k0 < K; k0 += 16) {
    float a0=0.f,a1=0.f,a2=0.f,a3=0.f;
    int grow = bm + ar;
    if (grow < M) {
      const float* ap = A + (size_t)grow * lda + (k0 + ak);
      int rem = K - (k0 + ak);
      if (rem >= 4) { a0=ap[0]; a1=ap[1]; a2=ap[2]; a3=ap[3]; }
      else { if(rem>0)a0=ap[0]; if(rem>1)a1=ap[1]; if(rem>2)a2=ap[2]; }
    }
    float w0=0.f,w1=0.f,w2=0.f,w3=0.f;
    int gn = bn + ar;
    if (gn < Nout) {
      const float* wp = W + (size_t)gn * ldw + (k0 + ak);
      int rem = K - (k0 + ak);
      if (rem >= 4) { w0=wp[0]; w1=wp[1]; w2=wp[2]; w3=wp[3]; }
      else { if(rem>0)w0=wp[0]; if(rem>1)w1=wp[1]; if(rem>2)w2=wp[2]; }
    }
    __syncthreads();
    As[ak+0][ar]=a0; As[ak+1][ar]=a1; As[ak+2][ar]=a2; As[ak+3][ar]=a3;
    Ws[ak+0][ar]=w0; Ws[ak+1][ar]=w1; Ws[ak+2][ar]=w2; Ws[ak+3][ar]=w3;
    __syncthreads();
#pragma unroll
    for (int kk = 0; kk < 16; kk++) {
      float4 av = *reinterpret_cast<const float4*>(&As[kk][ty*4]);
      float4 wv = *reinterpret_cast<const float4*>(&Ws[kk][tx*4]);
      float aa[4] = {av.x,av.y,av.z,av.w};
      float ww[4] = {wv.x,wv.y,wv.z,wv.w};
#pragma unroll
      for (int i=0;i<4;i++)
#pragma unroll
        for (int j=0;j<4;j++) acc[i][j] += aa[i]*ww[j];
    }
  }
#pragma unroll
  for (int i=0;i<4;i++){
    int m = bm + ty*4 + i;
    if (m >= M) continue;
#pragma unroll
    for (int j=0;j<4;j++){
      int n = bn + tx*4 + j;
      if (n >= Nout) continue;
      float v = acc[i][j];
      if (EPI==0)      v = v * scale[n] + shift[n];
      else if (EPI==1) v = v + shift[n];
      else             v = (v + shift[n]) * gmul;
      if (ACT==1)      v = v > 0.f ? v : 0.2f*v;
      else if (ACT==2) v = sinf(v);
      C[(size_t)m*ldc + n] = v;
    }
  }
}

// ---------------------------------------------------------------------------
// Fused 8-layer SIREN + head, split-bf16 MFMA, v2:
//  - 256 threads = 4 waves; each wave owns 32 wave-private rows in LDS.
//  - B-frags loaded directly from frag-major global hi/lo planes (L2-hot,
//    perfectly coalesced 16B/lane) -> no W staging, no staging barriers,
//    no B-side bitops.
//  - act: packed u32 (hi<<16|lo), row stride 128, XOR swizzle at 4-dword
//    granularity (group g stored at g^row) -> conflict-free, 16B aligned.
// Validated fragment mappings (round 4): A[m=lane&31][k=(lane>>5)*8+j],
// B[n=lane&31][k=(lane>>5)*8+j], D[col=lane&31][row=(reg&3)+8*(reg>>2)+4*(lane>>5)].
// ---------------------------------------------------------------------------
__global__ __launch_bounds__(256, 2) void siren_fused_k(
    const void* __restrict__ upin,
    const ushort_t* __restrict__ whi, const ushort_t* __restrict__ wlo,
    const float* __restrict__ W0c, const float* __restrict__ S0c, const float* __restrict__ H0c,
    const float* __restrict__ SRc, const float* __restrict__ HRc,
    const float* __restrict__ WFc, const float* __restrict__ BFc,
    float* __restrict__ logits, const int* __restrict__ flag)
{
  __shared__ __align__(16) uint act[4*32*128];     // 65536 B (4 wave-private slabs)
  __shared__ float intile[4*32*8];                 // 4096 B
  __shared__ float w0s[128*9];                     // 4608 B
  __shared__ float wfs[128];
  __shared__ float bfs[1];

  const int tid  = threadIdx.x;
  const int lane = tid & 63;
  const int wv   = tid >> 6;          // 0..3
  const int np   = lane & 31;
  const int hb2  = lane >> 5;         // 0..1 (k-half)
  const int rowbase = blockIdx.x * 128 + wv * 32;
  const int isbf = flag[0];
  uint*  actw = act + wv*32*128;
  float* intw = intile + wv*32*8;

  // ---- stage shared small stuff + per-wave input tile ----
  for (int e = tid; e < 128*7; e += 256) w0s[(e/7)*9 + (e%7)] = W0c[e];
  if (tid < 128) wfs[tid] = WFc[tid];
  if (tid == 0) bfs[0] = BFc[0];
  for (int e = lane; e < 32*7; e += 64) {
    int r = e/7, k = e%7;
    int gr = rowbase + r;
    float v = 0.f;
    if (gr < UP_ROWS)
      v = isbf ? b2f(((const bf16*)upin)[(size_t)gr*7+k]) : ((const float*)upin)[(size_t)gr*7+k];
    intw[r*8+k] = v;
  }
  __syncthreads();

  // ---- layer 0 (7 -> 128), write into swizzled D-slots ----
#pragma unroll
  for (int t = 0; t < 4; t++) {
    int c = t*32 + np;
    float s = S0c[c], b = H0c[c];
#pragma unroll
    for (int reg = 0; reg < 16; reg++) {
      int r = (reg&3) + 8*(reg>>2) + 4*hb2;
      float a = 0.f;
#pragma unroll
      for (int k = 0; k < 7; k++) a += intw[r*8+k]*w0s[c*9+k];
      float x = __sinf(a*s + b);
      uint hbi = f2bf_bits(x);
      uint lbi = f2bf_bits(x - __uint_as_float(hbi<<16));
      int col = (c & 3) | ((((c>>2) ^ r) & 31) << 2);
      actw[r*128 + col] = (hbi<<16) | lbi;
    }
  }

  // ---- layers 1..7 (128 -> 128) ----
  for (int l = 0; l < 7; l++) {
    float sc[4], sh[4];
#pragma unroll
    for (int t=0;t<4;t++){ sc[t] = SRc[l*128 + t*32 + np]; sh[t] = HRc[l*128 + t*32 + np]; }
    Acc16 acc[4];
#pragma unroll
    for (int t=0;t<4;t++)
#pragma unroll
      for (int i=0;i<16;i++) acc[t].f[i] = 0.f;

#pragma unroll 1
    for (int Q = 0; Q < 4; Q++) {
#pragma unroll
      for (int ks = 0; ks < 2; ks++) {
        int g0 = (Q*32 + ks*16 + hb2*8) >> 2;
        uint4 a0 = *(const uint4*)&actw[np*128 + ((g0 ^ np) << 2)];
        uint4 a1 = *(const uint4*)&actw[np*128 + (((g0+1) ^ np) << 2)];
        uint au[8] = {a0.x,a0.y,a0.z,a0.w,a1.x,a1.y,a1.z,a1.w};
        FragAB ahi, alo;
#pragma unroll
        for (int p=0;p<4;p++){
          ahi.u[p] = (au[2*p]>>16)     | (au[2*p+1] & 0xFFFF0000u);
          alo.u[p] = (au[2*p]&0xFFFFu) | (au[2*p+1]<<16);
        }
        size_t fb = ((size_t)(((l*4 + Q)*2 + ks)*4) << 9) + (size_t)lane*8;
        FragB bh[4], bl[4];
#pragma unroll
        for (int t=0;t<4;t++){
          bh[t].q = *(const uint4*)(whi + fb + (size_t)t*512);
          bl[t].q = *(const uint4*)(wlo + fb + (size_t)t*512);
        }
#pragma unroll
        for (int t=0;t<4;t++){
          acc[t].v = __builtin_amdgcn_mfma_f32_32x32x16_bf16(ahi.v, bh[t].v, acc[t].v, 0,0,0);
          acc[t].v = __builtin_amdgcn_mfma_f32_32x32x16_bf16(alo.v, bh[t].v, acc[t].v, 0,0,0);
          acc[t].v = __builtin_amdgcn_mfma_f32_32x32x16_bf16(ahi.v, bl[t].v, acc[t].v, 0,0,0);
        }
      }
    }
    // epilogue: scale/shift + sin + split-pack back to wave-private act
#pragma unroll
    for (int t=0;t<4;t++){
      int c = t*32 + np;
#pragma unroll
      for (int reg=0;reg<16;reg++){
        int r = (reg&3) + 8*(reg>>2) + 4*hb2;
        float x = __sinf(acc[t].f[reg]*sc[t] + sh[t]);
        uint hbi = f2bf_bits(x);
        uint lbi = f2bf_bits(x - __uint_as_float(hbi<<16));
        int col = (c & 3) | ((((c>>2) ^ r) & 31) << 2);
        actw[r*128 + col] = (hbi<<16) | lbi;
      }
    }
    __syncthreads();   // cheap safety fence (wave-private data; 7 total)
  }

  // ---- head (128 -> 1): 2 lanes per row (k-halves) ----
  {
    float a = 0.f;
#pragma unroll
    for (int g = 0; g < 16; g++) {
      int gg = hb2*16 + g;
      uint4 u = *(const uint4*)&actw[np*128 + ((gg ^ np) << 2)];
      int kb = gg*4;
      float x0 = __uint_as_float(u.x & 0xFFFF0000u) + __uint_as_float(u.x<<16);
      float x1 = __uint_as_float(u.y & 0xFFFF0000u) + __uint_as_float(u.y<<16);
      float x2 = __uint_as_float(u.z & 0xFFFF0000u) + __uint_as_float(u.z<<16);
      float x3 = __uint_as_float(u.w & 0xFFFF0000u) + __uint_as_float(u.w<<16);
      a += x0*wfs[kb] + x1*wfs[kb+1] + x2*wfs[kb+2] + x3*wfs[kb+3];
    }
    a += __shfl_xor(a, 32, 64);
    int gr = rowbase + np;
    if (hb2 == 0 && gr < UP_ROWS) logits[gr] = a + bfs[0];
  }
}

// ---------------------------------------------------------------------------
__global__ void featin_k(const void* __restrict__ ldx, const void* __restrict__ pos,
                         float* __restrict__ xf, const int* __restrict__ flag){
  int i = blockIdx.x*256 + threadIdx.x;
  if (i >= N_PTS*35) return;
  int n = i / 35, c = i % 35;
  float v;
  if (flag[0]) {
    v = (c < 3) ? b2f(((const bf16*)ldx)[n*3+c]) : b2f(((const bf16*)pos)[n*32 + (c-3)]);
  } else {
    v = (c < 3) ? ((const float*)ldx)[n*3+c] : ((const float*)pos)[n*32 + (c-3)];
  }
  xf[(size_t)n*227 + c] = v;
}

__global__ void gather_e_k(const float* __restrict__ xf, int coff, int CIN,
                           const int* __restrict__ idx, float* __restrict__ e,
                           int n0, int np){
  int W2 = 2*CIN;
  int i = blockIdx.x*256 + threadIdx.x;
  if (i >= np*KNN_K*W2) return;
  int c = i % W2; int ek = i / W2;
  int nl = ek / KNN_K, k = ek % KNN_K;
  int n = n0 + nl;
  int j = idx[n*KNN_K + k];
  float out;
  if (c < CIN) out = xf[(size_t)j*227 + coff + c] - xf[(size_t)n*227 + coff + c];
  else         out = xf[(size_t)n*227 + coff + (c-CIN)];
  e[(size_t)ek*W2 + c] = out;
}

__global__ void kmax_k(const float* __restrict__ e2, int C, float* __restrict__ f1,
                       int n0, int np){
  int i = blockIdx.x*256 + threadIdx.x;
  if (i >= np*C) return;
  int nl = i / C, c = i % C;
  float v = -1e30f;
  for (int k=0;k<KNN_K;k++) v = fmaxf(v, e2[((size_t)nl*KNN_K+k)*C + c]);
  f1[(size_t)(n0+nl)*C + c] = v;
}

template<int C>
__global__ __launch_bounds__(256) void reduce1_k(const float* __restrict__ X, int n,
                                                 float* __restrict__ pmax, float* __restrict__ psum){
  const int tid = threadIdx.x;
  const int c = tid % C;
  const int r0 = tid / C;
  const int TPR = 256 / C;
  float vmax = -1e30f, vsum = 0.f;
  for (int row = blockIdx.x * TPR + r0; row < n; row += gridDim.x * TPR) {
    float v = X[(size_t)row * C + c];
    vmax = fmaxf(vmax, v); vsum += v;
  }
  __shared__ float smax[256], ssum[256];
  smax[tid]=vmax; ssum[tid]=vsum;
  __syncthreads();
  if (tid < C) {
    for (int q=1;q<TPR;q++){ vmax=fmaxf(vmax, smax[q*C+c]); vsum += ssum[q*C+c]; }
    pmax[blockIdx.x*C + c] = vmax; psum[blockIdx.x*C + c] = vsum;
  }
}

template<int C>
__global__ void reduce2_k(const float* __restrict__ pmax, const float* __restrict__ psum,
                          int nblk, float invn, float* __restrict__ fmaxo, float* __restrict__ favgo){
  int c = threadIdx.x; if (c >= C) return;
  float vmax=-1e30f, vsum=0.f;
  for (int b=0;b<nblk;b++){ vmax=fmaxf(vmax,pmax[b*C+c]); vsum+=psum[b*C+c]; }
  fmaxo[c]=vmax; favgo[c]=vsum*invn;
}

__global__ void concat_k(const float* __restrict__ xf, int coff, int CF,
                         const float* __restrict__ f1, int C,
                         const float* __restrict__ fmax, const float* __restrict__ favg,
                         float* __restrict__ h, int n0, int np){
  int W = CF + 3*C;
  int i = blockIdx.x*256 + threadIdx.x;
  if (i >= np*W) return;
  int nl = i / W, c = i % W;
  int n = n0 + nl;
  float v;
  if (c < CF)          v = xf[(size_t)n*227 + coff + c];
  else if (c < CF+C)   v = f1[(size_t)n*C + (c-CF)];
  else if (c < CF+2*C) v = fmax[c-CF-C];
  else                 v = favg[c-CF-2*C];
  h[(size_t)nl*W + c] = v;
}

__global__ void norms_k(const float* __restrict__ xf, float* __restrict__ nr){
  int n = blockIdx.x*256 + threadIdx.x;
  if (n >= N_PTS) return;
  const float* p = xf + (size_t)n*227 + 35;
  float s = 0.f;
  for (int d=0;d<64;d++) s += p[d]*p[d];
  nr[n] = s;
}

#define BUBBLE() \
  if (tv4 > tv3){ float tf=tv3; tv3=tv4; tv4=tf; int ti=tj3; tj3=tj4; tj4=ti; } \
  if (tv3 > tv2){ float tf=tv2; tv2=tv3; tv3=tf; int ti=tj2; tj2=tj3; tj3=ti; } \
  if (tv2 > tv1){ float tf=tv1; tv1=tv2; tv2=tf; int ti=tj1; tj1=tj2; tj2=ti; } \
  if (tv1 > tv0){ float tf=tv0; tv0=tv1; tv1=tf; int ti=tj0; tj0=tj1; tj1=ti; }

__global__ __launch_bounds__(256) void knn_k(const float* __restrict__ xf,
                                             const float* __restrict__ nr,
                                             float* __restrict__ candv, int* __restrict__ candi){
  __shared__ __align__(16) float4 sj[128][16];
  __shared__ float snorm[128];
  const int i = blockIdx.x*256 + threadIdx.x;
  const int part = blockIdx.y;
  const int jbeg = part * (N_PTS / JSPLIT);
  const int jend = jbeg + (N_PTS / JSPLIT);
  float4 fr[16];
  {
    const float* p = xf + (size_t)i*227 + 35;
#pragma unroll
    for (int q=0;q<16;q++) fr[q] = make_float4(p[4*q],p[4*q+1],p[4*q+2],p[4*q+3]);
  }
  const float ni = nr[i];
  float tv0=-1e30f,tv1=-1e30f,tv2=-1e30f,tv3=-1e30f,tv4=-1e30f;
  int tj0=0,tj1=0,tj2=0,tj3=0,tj4=0;
  for (int j0 = jbeg; j0 < jend; j0 += 128) {
    __syncthreads();
    for (int u = threadIdx.x; u < 128*64; u += 256) {
      int jj = u >> 6, d = u & 63;
      int j = j0 + jj;
      ((float*)sj)[u] = (j < jend) ? xf[(size_t)j*227 + 35 + d] : 0.f;
    }
    if (threadIdx.x < 128) {
      int j = j0 + threadIdx.x;
      snorm[threadIdx.x] = (j < jend) ? nr[j] : 1e30f;
    }
    __syncthreads();
    for (int jj = 0; jj < 128; jj++) {
      float a0=0.f,a1=0.f,a2=0.f,a3=0.f;
#pragma unroll
      for (int q=0;q<16;q++){
        float4 s = sj[jj][q];
        a0 += fr[q].x*s.x; a1 += fr[q].y*s.y; a2 += fr[q].z*s.z; a3 += fr[q].w*s.w;
      }
      int j = j0 + jj;
      float v = 2.f*((a0+a1)+(a2+a3)) - ni - snorm[jj];
      if (j != i && v > tv4) {
        tv4 = v; tj4 = j;
        BUBBLE();
      }
    }
  }
  size_t base = ((size_t)part*N_PTS + i)*KNN_K;
  candv[base+0]=tv0; candv[base+1]=tv1; candv[base+2]=tv2; candv[base+3]=tv3; candv[base+4]=tv4;
  candi[base+0]=tj0; candi[base+1]=tj1; candi[base+2]=tj2; candi[base+3]=tj3; candi[base+4]=tj4;
}

__global__ void knn_merge_k(const float* __restrict__ candv, const int* __restrict__ candi,
                            int* __restrict__ out){
  int i = blockIdx.x*256 + threadIdx.x;
  if (i >= N_PTS) return;
  float tv0=-1e30f,tv1=-1e30f,tv2=-1e30f,tv3=-1e30f,tv4=-1e30f;
  int tj0=0,tj1=0,tj2=0,tj3=0,tj4=0;
  for (int p=0;p<JSPLIT;p++){
    size_t base = ((size_t)p*N_PTS + i)*KNN_K;
    for (int s=0;s<KNN_K;s++){
      float v = candv[base+s]; int j = candi[base+s];
      if (v > tv4){
        tv4 = v; tj4 = j;
        BUBBLE();
      }
    }
  }
  out[i*KNN_K+0]=tj0; out[i*KNN_K+1]=tj1; out[i*KNN_K+2]=tj2; out[i*KNN_K+3]=tj3; out[i*KNN_K+4]=tj4;
}

__global__ __launch_bounds__(64) void softgather_k(const float* __restrict__ logits,
                                                   const int* __restrict__ up_idx,
                                                   const float* __restrict__ xf,
                                                   float* __restrict__ z){
  __shared__ float lw[KUP]; __shared__ int li[KUP];
  int m = blockIdx.x;
  int tid = threadIdx.x;
  if (tid < KUP){ lw[tid] = logits[(size_t)m*KUP + tid]; li[tid] = up_idx[(size_t)m*KUP + tid]; }
  __syncthreads();
  float mx = -1e30f;
  for (int k=0;k<KUP;k++) mx = fmaxf(mx, lw[k]);
  __syncthreads();
  if (tid < KUP) lw[tid] = expf(lw[tid]-mx);
  __syncthreads();
  float s = 0.f;
  for (int k=0;k<KUP;k++) s += lw[k];
  float inv = 1.f/s;
  for (int c = tid; c < 227; c += 64){
    float acc = 0.f;
    for (int k=0;k<KUP;k++) acc += lw[k] * xf[(size_t)li[k]*227 + c];
    z[(size_t)m*227 + c] = acc*inv;
  }
}

__global__ void final_k(const float* __restrict__ h, const float* __restrict__ wf,
                        const float* __restrict__ bfp, void* __restrict__ out,
                        int r0, int rows, const int* __restrict__ flag){
  int m = blockIdx.x*256 + threadIdx.x;
  if (m >= rows) return;
  float hv[16];
#pragma unroll
  for (int d=0;d<16;d++) hv[d] = h[(size_t)m*16 + d];
#pragma unroll
  for (int o=0;o<3;o++){
    float acc = 0.f;
#pragma unroll
    for (int d=0;d<16;d++) acc += hv[d]*wf[o*16+d];
    float v = acc + bfp[o];
    if (!(fabsf(v) < 1e30f)) v = 777.0f;   // NaN/inf canary
    size_t oi = (size_t)(r0+m)*3+o;
    if (flag[0]) ((bf16*)out)[oi] = __float2bfloat16(v);
    else         ((float*)out)[oi] = v;
  }
}

// ---------------------------------------------------------------------------
extern "C" void kernel_launch(void* const* d_in, const int* in_sizes, int n_in,
                              void* d_out, int out_size, void* d_ws, size_t ws_size,
                              hipStream_t stream) {
  const int *idx0  = (const int*)d_in[3];
  const int *upidx = (const int*)d_in[37];

  // ---- workspace layout (floats) ----
  float* ws = (float*)d_ws;
  float* x_feat = ws;                     // [N,227]
  float* f1b    = ws + 3602944;           // [N,128]
  float* pmax   = ws + 5634560;
  float* psum   = ws + 5667328;
  float* fmaxv  = ws + 5700096;
  float* favgv  = ws + 5700224;
  int*   flag   = (int*)(ws + 5700352);
  int*   idx1   = (int*)(ws + 5700368);   // N*5
  float* nrm    = ws + 5779728;           // N
  float* logits = ws + 5795600;           // UP_ROWS
  float* wcvt   = ws + 6508352;           // 706,020 fp32 weights
  float* S      = ws + 7214400;           // scratch arena
  ushort_t* whi = (ushort_t*)(S + 9662464);   // 114688 bf16 hi plane
  ushort_t* wlo = whi + 114688;               // 114688 bf16 lo plane

  const size_t NEED = (size_t)(7214400 + 9662464 + 114688) * 4;  // ~68 MB
  if (ws_size < NEED) {
    fillmark_k<<<CDIV(out_size,256),256,0,stream>>>((bf16*)d_out, out_size);
    return;
  }

  // ---- dtype flag + one-shot weight conversion to fp32 ----
  flag_k<<<1,64,0,stream>>>((const uint*)d_in[2], flag);
  CvtTab tab;
  int wcoff = 0, seg = 0;
  auto CVT = [&](int i, int n)->const float* {
    tab.src[seg] = d_in[i]; tab.start[seg] = wcoff; seg++;
    const float* p = wcvt + wcoff; wcoff += n;
    return p;
  };
  const float *E0W1=CVT(4,8960),  *E0S1=CVT(5,128),  *E0H1=CVT(6,128),
              *E0W2=CVT(7,8192),  *E0B2=CVT(8,64);
  const float *F0W1=CVT(9,43584), *F0S1=CVT(10,192), *F0H1=CVT(11,192),
              *F0W2=CVT(12,24576),*F0S2=CVT(13,128), *F0H2=CVT(14,128),
              *F0W3=CVT(15,8192), *F0S3=CVT(16,64),  *F0H3=CVT(17,64),
              *F0W4=CVT(18,4096), *F0B4=CVT(19,64);
  const float *E1W1=CVT(20,32768),*E1S1=CVT(21,256), *E1H1=CVT(22,256),
              *E1W2=CVT(23,32768),*E1B2=CVT(24,128);
  const float *F1W1=CVT(25,172032),*F1S1=CVT(26,384),*F1H1=CVT(27,384),
              *F1W2=CVT(28,98304),*F1S2=CVT(29,256), *F1H2=CVT(30,256),
              *F1W3=CVT(31,32768),*F1S3=CVT(32,128), *F1H3=CVT(33,128),
              *F1W4=CVT(34,16384),*F1B4=CVT(35,128);
  const float *UPW0=CVT(38,896),  *UPS0=CVT(39,128), *UPH0=CVT(40,128),
              *UPWR=CVT(41,114688),*UPSR=CVT(42,896),*UPHR=CVT(43,896),
              *UPWF=CVT(44,128),  *UPBF=CVT(45,1);
  const float *DW0=CVT(46,58112), *DB0=CVT(47,256),
              *DW1=CVT(48,32768), *DB1=CVT(49,128),
              *DW2=CVT(50,8192),  *DB2=CVT(51,64),
              *DW3=CVT(52,2048),  *DB3=CVT(53,32),
              *DW4=CVT(54,512),   *DB4=CVT(55,16),
              *DWF=CVT(56,48),    *DBF=CVT(57,3);
  cvt_all_k<<<CDIV(wcoff,256),256,0,stream>>>(tab, wcvt, flag, wcoff);

  // frag-major split-bf16 pack of the SIREN 128x128 weights
  packfrag_k<<<CDIV(114688,256),256,0,stream>>>(UPWR, whi, wlo, 114688);

  const float invN = 1.f/(float)N_PTS;
  const int CHP = 3072;    // edge-phase point chunk
  const int CHN = 8192;    // fc-phase row chunk
  const int CHD = 4096;    // decoder row chunk

  featin_k<<<CDIV(N_PTS*35,256),256,0,stream>>>(d_in[1], d_in[2], x_feat, flag);

  // ---- phase 1: emb block 0
  for (int n0 = 0; n0 < N_PTS; n0 += CHP) {
    int np = N_PTS - n0; if (np > CHP) np = CHP;
    int ne = np * KNN_K;
    float* eA = S;
    float* eB = S + 1075200;
    gather_e_k<<<CDIV(ne*70,256),256,0,stream>>>(x_feat, 0, 35, idx0, eA, n0, np);
    gemm_k<0,1><<<dim3(CDIV(ne,64),2),256,0,stream>>>(eA,70, E0W1,70, E0S1,E0H1,0.f, eB,128, ne,128,70);
    gemm_k<1,0><<<dim3(CDIV(ne,64),1),256,0,stream>>>(eB,128, E0W2,128, nullptr,E0B2,0.f, eA,64, ne,64,128);
    kmax_k<<<CDIV(np*64,256),256,0,stream>>>(eA, 64, f1b, n0, np);
  }
  reduce1_k<64><<<256,256,0,stream>>>(f1b, N_PTS, pmax, psum);
  reduce2_k<64><<<1,64,0,stream>>>(pmax, psum, 256, invN, fmaxv, favgv);
  for (int n0 = 0; n0 < N_PTS; n0 += CHN) {
    int np = N_PTS - n0; if (np > CHN) np = CHN;
    float* h  = S;
    float* a1 = S + 1859584;
    int gx = CDIV(np,64);
    concat_k<<<CDIV(np*227,256),256,0,stream>>>(x_feat,0,35, f1b,64, fmaxv,favgv, h, n0, np);
    gemm_k<0,1><<<dim3(gx,3),256,0,stream>>>(h,227,  F0W1,227, F0S1,F0H1,0.f, a1,192, np,192,227);
    gemm_k<0,1><<<dim3(gx,2),256,0,stream>>>(a1,192, F0W2,192, F0S2,F0H2,0.f, h,128,  np,128,192);
    gemm_k<0,1><<<dim3(gx,1),256,0,stream>>>(h,128,  F0W3,128, F0S3,F0H3,0.f, a1,64,  np,64,128);
    gemm_k<1,0><<<dim3(gx,1),256,0,stream>>>(a1,64,  F0W4,64,  nullptr,F0B4,0.f, x_feat+(size_t)n0*227+35,227, np,64,64);
  }

  // ---- phase 2: dynamic KNN
  norms_k<<<CDIV(N_PTS,256),256,0,stream>>>(x_feat, nrm);
  {
    float* candv = S;
    int*   candi = (int*)(S + 634880);
    knn_k<<<dim3(N_PTS/256, JSPLIT),256,0,stream>>>(x_feat, nrm, candv, candi);
    knn_merge_k<<<CDIV(N_PTS,256),256,0,stream>>>(candv, candi, idx1);
  }

  // ---- phase 3: emb block 1
  for (int n0 = 0; n0 < N_PTS; n0 += CHP) {
    int np = N_PTS - n0; if (np > CHP) np = CHP;
    int ne = np * KNN_K;
    float* eA = S;
    float* eB = S + 1966080;
    gather_e_k<<<CDIV(ne*128,256),256,0,stream>>>(x_feat, 35, 64, idx1, eA, n0, np);
    gemm_k<0,1><<<dim3(CDIV(ne,64),4),256,0,stream>>>(eA,128, E1W1,128, E1S1,E1H1,0.f, eB,256, ne,256,128);
    gemm_k<1,0><<<dim3(CDIV(ne,64),2),256,0,stream>>>(eB,256, E1W2,256, nullptr,E1B2,0.f, eA,128, ne,128,256);
    kmax_k<<<CDIV(np*128,256),256,0,stream>>>(eA, 128, f1b, n0, np);
  }
  reduce1_k<128><<<256,256,0,stream>>>(f1b, N_PTS, pmax, psum);
  reduce2_k<128><<<1,128,0,stream>>>(pmax, psum, 256, invN, fmaxv, favgv);
  for (int n0 = 0; n0 < N_PTS; n0 += CHN) {
    int np = N_PTS - n0; if (np > CHN) np = CHN;
    float* h  = S;
    float* a1 = S + 3670016;
    int gx = CDIV(np,64);
    concat_k<<<CDIV(np*448,256),256,0,stream>>>(x_feat,35,64, f1b,128, fmaxv,favgv, h, n0, np);
    gemm_k<0,1><<<dim3(gx,6),256,0,stream>>>(h,448,  F1W1,448, F1S1,F1H1,0.f, a1,384, np,384,448);
    gemm_k<0,1><<<dim3(gx,4),256,0,stream>>>(a1,384, F1W2,384, F1S2,F1H2,0.f, h,256,  np,256,384);
    gemm_k<0,1><<<dim3(gx,2),256,0,stream>>>(h,256,  F1W3,256, F1S3,F1H3,0.f, a1,128, np,128,256);
    gemm_k<1,0><<<dim3(gx,2),256,0,stream>>>(a1,128, F1W4,128, nullptr,F1B4,0.f, x_feat+(size_t)n0*227+99,227, np,128,128);
  }

  // ---- phase 4: fused split-bf16 MFMA SIREN v2 -> logits; softmax gather -> z
  siren_fused_k<<<CDIV(UP_ROWS,128),256,0,stream>>>(
      d_in[36], whi, wlo, UPW0, UPS0, UPH0, UPSR, UPHR, UPWF, UPBF, logits, flag);
  float* zbuf = S;                 // [M,227]
  softgather_k<<<M_PTS,64,0,stream>>>(logits, upidx, x_feat, zbuf);

  // ---- phase 5: SIREN decoder
  {
    float* A  = S + 8089600;            // [CHD,256]
    float* Bb = S + 8089600 + 1048576;  // [CHD,128]
    for (int r0 = 0; r0 < M_PTS; r0 += CHD) {
      int rows = M_PTS - r0; if (rows > CHD) rows = CHD;
      int gx = CDIV(rows,64);
      gemm_k<2,2><<<dim3(gx,4),256,0,stream>>>(zbuf + (size_t)r0*227,227, DW0,227, nullptr,DB0,30.f, A,256,  rows,256,227);
      gemm_k<1,2><<<dim3(gx,2),256,0,stream>>>(A,256,  DW1,256, nullptr,DB1,0.f, Bb,128, rows,128,256);
      gemm_k<1,2><<<dim3(gx,1),256,0,stream>>>(Bb,128, DW2,128, nullptr,DB2,0.f, A,64,   rows,64,128);
      gemm_k<1,2><<<dim3(gx,1),256,0,stream>>>(A,64,   DW3,64,  nullptr,DB3,0.f, Bb,32,  rows,32,64);
      gemm_k<1,2><<<dim3(gx,1),256,0,stream>>>(Bb,32,  DW4,32,  nullptr,DB4,0.f, A,16,   rows,16,32);
      final_k<<<CDIV(rows,256),256,0,stream>>>(A, DWF, DBF, d_out, r0, rows, flag);
    }
  }
}

// Round 6
// 3747.598 us; speedup vs baseline: 2.0671x; 1.0054x over previous
//
#include <hip/hip_runtime.h>
#include <hip/hip_bf16.h>
#include <math.h>

#define N_PTS 15872
#define M_PTS 35637
#define KNN_K 5
#define KUP   20
#define UP_ROWS (M_PTS * KUP)   // 712740
#define NTILE (N_PTS/32)        // 496 i/j tiles
#define CDIV(a,b) (((a)+(b)-1)/(b))

typedef __hip_bfloat16 bf16;
typedef unsigned int uint;
typedef unsigned short ushort_t;
__device__ __forceinline__ float b2f(bf16 x){ return __bfloat162float(x); }

// round-to-nearest-even fp32 -> bf16 bit pattern (finite inputs)
__device__ __forceinline__ uint f2bf_bits(float x){
  uint u = __float_as_uint(x);
  return (u + 0x7FFFu + ((u>>16)&1u)) >> 16;
}

typedef __attribute__((ext_vector_type(8))) short bf16x8;
typedef __attribute__((ext_vector_type(16))) float f32x16;
union FragAB { bf16x8 v; uint u[4]; };
union FragB  { bf16x8 v; uint4 q; };
union Acc16  { f32x16 v; float f[16]; };

// ---------------------------------------------------------------------------
__global__ void flag_k(const uint* __restrict__ pos_raw, int* __restrict__ flag){
  if (threadIdx.x == 0 && blockIdx.x == 0)
    flag[0] = (pos_raw[0] == 0x3F800000u) ? 1 : 0;
}

// one-shot conversion of ALL weight arrays (bf16 or fp32 per flag) to fp32
struct CvtTab { const void* src[52]; int start[52]; };
__global__ __launch_bounds__(256) void cvt_all_k(CvtTab tab, float* __restrict__ dst,
                                                 const int* __restrict__ flag, int total){
  int i = blockIdx.x*256 + threadIdx.x;
  if (i >= total) return;
  int s = 0;
#pragma unroll 1
  for (int k = 1; k < 52; k++) if (tab.start[k] <= i) s = k;
  int off = i - tab.start[s];
  float v = flag[0] ? b2f(((const bf16*)tab.src[s])[off]) : ((const float*)tab.src[s])[off];
  dst[i] = v;
}

// pack SIREN 128x128 weights into frag-major split-bf16 hi/lo planes.
__global__ void packfrag_k(const float* __restrict__ w, ushort_t* __restrict__ whi,
                           ushort_t* __restrict__ wlo, int n){
  int i = blockIdx.x*256 + threadIdx.x;
  if (i >= n) return;
  int j = i & 7;
  int lam = (i >> 3) & 63;
  int fg = i >> 9;
  int t = fg & 3, ks = (fg >> 2) & 1, Q = (fg >> 3) & 3, l = fg >> 5;
  int nn = t*32 + (lam & 31);
  int kk = Q*32 + ks*16 + (lam >> 5)*8 + j;
  float x = w[l*16384 + nn*128 + kk];
  uint hb = f2bf_bits(x);
  float hf = __uint_as_float(hb << 16);
  uint lb = f2bf_bits(x - hf);
  whi[i] = (ushort_t)hb;
  wlo[i] = (ushort_t)lb;
}

// pack KNN features into frag-major split-bf16 planes with norm augmentation.
// K=80: A-side (j): [2f, n_j, 1, 0...]; B-side (i): [f, -1, -n_i, 0...]
// slot i: e=i&7, lane=(i>>3)&63, rest=i>>9: kc=rest%5, jt=rest/5.
// n=jt*32+(lane&31), k=kc*16+(lane>>5)*8+e.
__global__ void packknn_k(const float* __restrict__ xf, const float* __restrict__ nr,
                          ushort_t* __restrict__ ahi, ushort_t* __restrict__ alo,
                          ushort_t* __restrict__ bhi, ushort_t* __restrict__ blo){
  int i = blockIdx.x*256 + threadIdx.x;
  if (i >= NTILE*5*64*8) return;
  int e = i & 7;
  int lane = (i >> 3) & 63;
  int rest = i >> 9;
  int kc = rest % 5, jt = rest / 5;
  int n = jt*32 + (lane & 31);
  int k = kc*16 + (lane >> 5)*8 + e;
  float f = (k < 64) ? xf[(size_t)n*227 + 35 + k] : 0.f;
  float av, bv;
  if (k < 64)      { av = 2.f*f;   bv = f; }
  else if (k == 64){ av = nr[n];   bv = -1.f; }
  else if (k == 65){ av = 1.f;     bv = -nr[n]; }
  else             { av = 0.f;     bv = 0.f; }
  uint ah = f2bf_bits(av); uint al = f2bf_bits(av - __uint_as_float(ah<<16));
  uint bh = f2bf_bits(bv); uint bl = f2bf_bits(bv - __uint_as_float(bh<<16));
  ahi[i] = (ushort_t)ah; alo[i] = (ushort_t)al;
  bhi[i] = (ushort_t)bh; blo[i] = (ushort_t)bl;
}

__global__ void fillmark_k(bf16* __restrict__ out, int n){
  int i = blockIdx.x*256 + threadIdx.x;
  if (i < n) out[i] = __float2bfloat16(12345.0f);
}

// ---------------------------------------------------------------------------
// Generic fused GEMM (fp32):  C[m,n] = ACT( EPI( sum_k A[m,k]*W[n,k] ) )
// EPI 0: v*scale[n]+shift[n]   EPI 1: v+shift[n]   EPI 2: (v+shift[n])*gmul
// ACT 0: none   ACT 1: lrelu(0.2)   ACT 2: sin
// ---------------------------------------------------------------------------
template<int EPI, int ACT>
__global__ __launch_bounds__(256) void gemm_k(
    const float* __restrict__ A, int lda,
    const float* __restrict__ W, int ldw,
    const float* __restrict__ scale, const float* __restrict__ shift,
    float gmul, float* __restrict__ C, int ldc,
    int M, int Nout, int K)
{
  __shared__ __align__(16) float As[16][64];
  __shared__ __align__(16) float Ws[16][64];
  const int tid = threadIdx.x;
  const int tx = tid & 15, ty = tid >> 4;
  const int bm = blockIdx.x * 64, bn = blockIdx.y * 64;
  const int ar = tid >> 2, ak = (tid & 3) * 4;
  float acc[4][4] = {};
  for (int k0 = 0; k0 < K; k0 += 16) {
    float a0=0.f,a1=0.f,a2=0.f,a3=0.f;
    int grow = bm + ar;
    if (grow < M) {
      const float* ap = A + (size_t)grow * lda + (k0 + ak);
      int rem = K - (k0 + ak);
      if (rem >= 4) { a0=ap[0]; a1=ap[1]; a2=ap[2]; a3=ap[3]; }
      else { if(rem>0)a0=ap[0]; if(rem>1)a1=ap[1]; if(rem>2)a2=ap[2]; }
    }
    float w0=0.f,w1=0.f,w2=0.f,w3=0.f;
    int gn = bn + ar;
    if (gn < Nout) {
      const float* wp = W + (size_t)gn * ldw + (k0 + ak);
      int rem = K - (k0 + ak);
      if (rem >= 4) { w0=wp[0]; w1=wp[1]; w2=wp[2]; w3=wp[3]; }
      else { if(rem>0)w0=wp[0]; if(rem>1)w1=wp[1]; if(rem>2)w2=wp[2]; }
    }
    __syncthreads();
    As[ak+0][ar]=a0; As[ak+1][ar]=a1; As[ak+2][ar]=a2; As[ak+3][ar]=a3;
    Ws[ak+0][ar]=w0; Ws[ak+1][ar]=w1; Ws[ak+2][ar]=w2; Ws[ak+3][ar]=w3;
    __syncthreads();
#pragma unroll
    for (int kk = 0; kk < 16; kk++) {
      float4 av = *reinterpret_cast<const float4*>(&As[kk][ty*4]);
      float4 wv = *reinterpret_cast<const float4*>(&Ws[kk][tx*4]);
      float aa[4] = {av.x,av.y,av.z,av.w};
      float ww[4] = {wv.x,wv.y,wv.z,wv.w};
#pragma unroll
      for (int i=0;i<4;i++)
#pragma unroll
        for (int j=0;j<4;j++) acc[i][j] += aa[i]*ww[j];
    }
  }
#pragma unroll
  for (int i=0;i<4;i++){
    int m = bm + ty*4 + i;
    if (m >= M) continue;
#pragma unroll
    for (int j=0;j<4;j++){
      int n = bn + tx*4 + j;
      if (n >= Nout) continue;
      float v = acc[i][j];
      if (EPI==0)      v = v * scale[n] + shift[n];
      else if (EPI==1) v = v + shift[n];
      else             v = (v + shift[n]) * gmul;
      if (ACT==1)      v = v > 0.f ? v : 0.2f*v;
      else if (ACT==2) v = sinf(v);
      C[(size_t)m*ldc + n] = v;
    }
  }
}

// ---------------------------------------------------------------------------
// MFMA KNN: scores S[j][i] = u_j . v_i = 2<f_i,f_j> - n_i - n_j via
// split-bf16 32x32x16 MFMA over K=80 (norm-augmented). A=j-tile (streamed),
// B=i-tile (register-resident). D: col=lane&31 -> i, row -> j. Top-5 per i
// kept in registers; half-lanes merged via shfl_xor(32).
// ---------------------------------------------------------------------------
__global__ __launch_bounds__(256) void knn_mfma_k(
    const ushort_t* __restrict__ ahi, const ushort_t* __restrict__ alo,
    const ushort_t* __restrict__ bhi, const ushort_t* __restrict__ blo,
    int* __restrict__ out)
{
  const int tid = threadIdx.x;
  const int lane = tid & 63;
  const int wv = tid >> 6;
  const int np = lane & 31;
  const int hb2 = lane >> 5;
  const int it = blockIdx.x*4 + wv;      // 0..495
  const int ig = it*32 + np;             // this lane's global i

  FragB vh[5], vl[5];
  {
    size_t bb = (size_t)(it*5)*512 + (size_t)lane*8;
#pragma unroll
    for (int kc=0;kc<5;kc++){
      vh[kc].q = *(const uint4*)(bhi + bb + kc*512);
      vl[kc].q = *(const uint4*)(blo + bb + kc*512);
    }
  }

  float tv[5] = {-1e30f,-1e30f,-1e30f,-1e30f,-1e30f};
  int   tj[5] = {0,0,0,0,0};

#pragma unroll 1
  for (int jt = 0; jt < NTILE; jt++){
    Acc16 acc;
#pragma unroll
    for (int q=0;q<16;q++) acc.f[q] = 0.f;
    size_t ab = (size_t)(jt*5)*512 + (size_t)lane*8;
#pragma unroll
    for (int kc=0;kc<5;kc++){
      FragB uh, ul;
      uh.q = *(const uint4*)(ahi + ab + kc*512);
      ul.q = *(const uint4*)(alo + ab + kc*512);
      acc.v = __builtin_amdgcn_mfma_f32_32x32x16_bf16(uh.v, vh[kc].v, acc.v, 0,0,0);
      acc.v = __builtin_amdgcn_mfma_f32_32x32x16_bf16(ul.v, vh[kc].v, acc.v, 0,0,0);
      acc.v = __builtin_amdgcn_mfma_f32_32x32x16_bf16(uh.v, vl[kc].v, acc.v, 0,0,0);
    }
    int jb = jt*32 + 4*hb2;
#pragma unroll
    for (int reg=0;reg<16;reg++){
      int j = jb + (reg&3) + 8*(reg>>2);
      float v = acc.f[reg];
      if (j != ig && v > tv[4]){
        tv[4] = v; tj[4] = j;
#pragma unroll
        for (int q=4;q>0;q--)
          if (tv[q] > tv[q-1]){ float tf=tv[q-1]; tv[q-1]=tv[q]; tv[q]=tf;
                                int ti=tj[q-1]; tj[q-1]=tj[q]; tj[q]=ti; }
      }
    }
  }

  // merge the two half-lane top-5 lists (same i, disjoint j sets)
#pragma unroll
  for (int s=0;s<5;s++){
    float ov = __shfl_xor(tv[s], 32, 64);
    int   oj = __shfl_xor(tj[s], 32, 64);
    if (ov > tv[4]){
      tv[4] = ov; tj[4] = oj;
#pragma unroll
      for (int q=4;q>0;q--)
        if (tv[q] > tv[q-1]){ float tf=tv[q-1]; tv[q-1]=tv[q]; tv[q]=tf;
                              int ti=tj[q-1]; tj[q-1]=tj[q]; tj[q]=ti; }
    }
  }
  if (hb2 == 0){
#pragma unroll
    for (int s=0;s<5;s++) out[ig*KNN_K + s] = tj[s];
  }
}

// ---------------------------------------------------------------------------
// Fused 8-layer SIREN + head, split-bf16 MFMA (validated round 5).
// ---------------------------------------------------------------------------
__global__ __launch_bounds__(256, 2) void siren_fused_k(
    const void* __restrict__ upin,
    const ushort_t* __restrict__ whi, const ushort_t* __restrict__ wlo,
    const float* __restrict__ W0c, const float* __restrict__ S0c, const float* __restrict__ H0c,
    const float* __restrict__ SRc, const float* __restrict__ HRc,
    const float* __restrict__ WFc, const float* __restrict__ BFc,
    float* __restrict__ logits, const int* __restrict__ flag)
{
  __shared__ __align__(16) uint act[4*32*128];
  __shared__ float intile[4*32*8];
  __shared__ float w0s[128*9];
  __shared__ float wfs[128];
  __shared__ float bfs[1];

  const int tid  = threadIdx.x;
  const int lane = tid & 63;
  const int wv   = tid >> 6;
  const int np   = lane & 31;
  const int hb2  = lane >> 5;
  const int rowbase = blockIdx.x * 128 + wv * 32;
  const int isbf = flag[0];
  uint*  actw = act + wv*32*128;
  float* intw = intile + wv*32*8;

  for (int e = tid; e < 128*7; e += 256) w0s[(e/7)*9 + (e%7)] = W0c[e];
  if (tid < 128) wfs[tid] = WFc[tid];
  if (tid == 0) bfs[0] = BFc[0];
  for (int e = lane; e < 32*7; e += 64) {
    int r = e/7, k = e%7;
    int gr = rowbase + r;
    float v = 0.f;
    if (gr < UP_ROWS)
      v = isbf ? b2f(((const bf16*)upin)[(size_t)gr*7+k]) : ((const float*)upin)[(size_t)gr*7+k];
    intw[r*8+k] = v;
  }
  __syncthreads();

#pragma unroll
  for (int t = 0; t < 4; t++) {
    int c = t*32 + np;
    float s = S0c[c], b = H0c[c];
#pragma unroll
    for (int reg = 0; reg < 16; reg++) {
      int r = (reg&3) + 8*(reg>>2) + 4*hb2;
      float a = 0.f;
#pragma unroll
      for (int k = 0; k < 7; k++) a += intw[r*8+k]*w0s[c*9+k];
      float x = __sinf(a*s + b);
      uint hbi = f2bf_bits(x);
      uint lbi = f2bf_bits(x - __uint_as_float(hbi<<16));
      int col = (c & 3) | ((((c>>2) ^ r) & 31) << 2);
      actw[r*128 + col] = (hbi<<16) | lbi;
    }
  }

  for (int l = 0; l < 7; l++) {
    float sc[4], sh[4];
#pragma unroll
    for (int t=0;t<4;t++){ sc[t] = SRc[l*128 + t*32 + np]; sh[t] = HRc[l*128 + t*32 + np]; }
    Acc16 acc[4];
#pragma unroll
    for (int t=0;t<4;t++)
#pragma unroll
      for (int i=0;i<16;i++) acc[t].f[i] = 0.f;

#pragma unroll 1
    for (int Q = 0; Q < 4; Q++) {
#pragma unroll
      for (int ks = 0; ks < 2; ks++) {
        int g0 = (Q*32 + ks*16 + hb2*8) >> 2;
        uint4 a0 = *(const uint4*)&actw[np*128 + ((g0 ^ np) << 2)];
        uint4 a1 = *(const uint4*)&actw[np*128 + (((g0+1) ^ np) << 2)];
        uint au[8] = {a0.x,a0.y,a0.z,a0.w,a1.x,a1.y,a1.z,a1.w};
        FragAB ahi, alo;
#pragma unroll
        for (int p=0;p<4;p++){
          ahi.u[p] = (au[2*p]>>16)     | (au[2*p+1] & 0xFFFF0000u);
          alo.u[p] = (au[2*p]&0xFFFFu) | (au[2*p+1]<<16);
        }
        size_t fb = ((size_t)(((l*4 + Q)*2 + ks)*4) << 9) + (size_t)lane*8;
        FragB bh[4], bl[4];
#pragma unroll
        for (int t=0;t<4;t++){
          bh[t].q = *(const uint4*)(whi + fb + (size_t)t*512);
          bl[t].q = *(const uint4*)(wlo + fb + (size_t)t*512);
        }
#pragma unroll
        for (int t=0;t<4;t++){
          acc[t].v = __builtin_amdgcn_mfma_f32_32x32x16_bf16(ahi.v, bh[t].v, acc[t].v, 0,0,0);
          acc[t].v = __builtin_amdgcn_mfma_f32_32x32x16_bf16(alo.v, bh[t].v, acc[t].v, 0,0,0);
          acc[t].v = __builtin_amdgcn_mfma_f32_32x32x16_bf16(ahi.v, bl[t].v, acc[t].v, 0,0,0);
        }
      }
    }
#pragma unroll
    for (int t=0;t<4;t++){
      int c = t*32 + np;
#pragma unroll
      for (int reg=0;reg<16;reg++){
        int r = (reg&3) + 8*(reg>>2) + 4*hb2;
        float x = __sinf(acc[t].f[reg]*sc[t] + sh[t]);
        uint hbi = f2bf_bits(x);
        uint lbi = f2bf_bits(x - __uint_as_float(hbi<<16));
        int col = (c & 3) | ((((c>>2) ^ r) & 31) << 2);
        actw[r*128 + col] = (hbi<<16) | lbi;
      }
    }
    __syncthreads();
  }

  {
    float a = 0.f;
#pragma unroll
    for (int g = 0; g < 16; g++) {
      int gg = hb2*16 + g;
      uint4 u = *(const uint4*)&actw[np*128 + ((gg ^ np) << 2)];
      int kb = gg*4;
      float x0 = __uint_as_float(u.x & 0xFFFF0000u) + __uint_as_float(u.x<<16);
      float x1 = __uint_as_float(u.y & 0xFFFF0000u) + __uint_as_float(u.y<<16);
      float x2 = __uint_as_float(u.z & 0xFFFF0000u) + __uint_as_float(u.z<<16);
      float x3 = __uint_as_float(u.w & 0xFFFF0000u) + __uint_as_float(u.w<<16);
      a += x0*wfs[kb] + x1*wfs[kb+1] + x2*wfs[kb+2] + x3*wfs[kb+3];
    }
    a += __shfl_xor(a, 32, 64);
    int gr = rowbase + np;
    if (hb2 == 0 && gr < UP_ROWS) logits[gr] = a + bfs[0];
  }
}

// ---------------------------------------------------------------------------
__global__ void featin_k(const void* __restrict__ ldx, const void* __restrict__ pos,
                         float* __restrict__ xf, const int* __restrict__ flag){
  int i = blockIdx.x*256 + threadIdx.x;
  if (i >= N_PTS*35) return;
  int n = i / 35, c = i % 35;
  float v;
  if (flag[0]) {
    v = (c < 3) ? b2f(((const bf16*)ldx)[n*3+c]) : b2f(((const bf16*)pos)[n*32 + (c-3)]);
  } else {
    v = (c < 3) ? ((const float*)ldx)[n*3+c] : ((const float*)pos)[n*32 + (c-3)];
  }
  xf[(size_t)n*227 + c] = v;
}

__global__ void gather_e_k(const float* __restrict__ xf, int coff, int CIN,
                           const int* __restrict__ idx, float* __restrict__ e,
                           int n0, int np){
  int W2 = 2*CIN;
  int i = blockIdx.x*256 + threadIdx.x;
  if (i >= np*KNN_K*W2) return;
  int c = i % W2; int ek = i / W2;
  int nl = ek / KNN_K, k = ek % KNN_K;
  int n = n0 + nl;
  int j = idx[n*KNN_K + k];
  float out;
  if (c < CIN) out = xf[(size_t)j*227 + coff + c] - xf[(size_t)n*227 + coff + c];
  else         out = xf[(size_t)n*227 + coff + (c-CIN)];
  e[(size_t)ek*W2 + c] = out;
}

__global__ void kmax_k(const float* __restrict__ e2, int C, float* __restrict__ f1,
                       int n0, int np){
  int i = blockIdx.x*256 + threadIdx.x;
  if (i >= np*C) return;
  int nl = i / C, c = i % C;
  float v = -1e30f;
  for (int k=0;k<KNN_K;k++) v = fmaxf(v, e2[((size_t)nl*KNN_K+k)*C + c]);
  f1[(size_t)(n0+nl)*C + c] = v;
}

template<int C>
__global__ __launch_bounds__(256) void reduce1_k(const float* __restrict__ X, int n,
                                                 float* __restrict__ pmax, float* __restrict__ psum){
  const int tid = threadIdx.x;
  const int c = tid % C;
  const int r0 = tid / C;
  const int TPR = 256 / C;
  float vmax = -1e30f, vsum = 0.f;
  for (int row = blockIdx.x * TPR + r0; row < n; row += gridDim.x * TPR) {
    float v = X[(size_t)row * C + c];
    vmax = fmaxf(vmax, v); vsum += v;
  }
  __shared__ float smax[256], ssum[256];
  smax[tid]=vmax; ssum[tid]=vsum;
  __syncthreads();
  if (tid < C) {
    for (int q=1;q<TPR;q++){ vmax=fmaxf(vmax, smax[q*C+c]); vsum += ssum[q*C+c]; }
    pmax[blockIdx.x*C + c] = vmax; psum[blockIdx.x*C + c] = vsum;
  }
}

template<int C>
__global__ void reduce2_k(const float* __restrict__ pmax, const float* __restrict__ psum,
                          int nblk, float invn, float* __restrict__ fmaxo, float* __restrict__ favgo){
  int c = threadIdx.x; if (c >= C) return;
  float vmax=-1e30f, vsum=0.f;
  for (int b=0;b<nblk;b++){ vmax=fmaxf(vmax,pmax[b*C+c]); vsum+=psum[b*C+c]; }
  fmaxo[c]=vmax; favgo[c]=vsum*invn;
}

__global__ void concat_k(const float* __restrict__ xf, int coff, int CF,
                         const float* __restrict__ f1, int C,
                         const float* __restrict__ fmax, const float* __restrict__ favg,
                         float* __restrict__ h, int n0, int np){
  int W = CF + 3*C;
  int i = blockIdx.x*256 + threadIdx.x;
  if (i >= np*W) return;
  int nl = i / W, c = i % W;
  int n = n0 + nl;
  float v;
  if (c < CF)          v = xf[(size_t)n*227 + coff + c];
  else if (c < CF+C)   v = f1[(size_t)n*C + (c-CF)];
  else if (c < CF+2*C) v = fmax[c-CF-C];
  else                 v = favg[c-CF-2*C];
  h[(size_t)nl*W + c] = v;
}

__global__ void norms_k(const float* __restrict__ xf, float* __restrict__ nr){
  int n = blockIdx.x*256 + threadIdx.x;
  if (n >= N_PTS) return;
  const float* p = xf + (size_t)n*227 + 35;
  float s = 0.f;
  for (int d=0;d<64;d++) s += p[d]*p[d];
  nr[n] = s;
}

__global__ __launch_bounds__(64) void softgather_k(const float* __restrict__ logits,
                                                   const int* __restrict__ up_idx,
                                                   const float* __restrict__ xf,
                                                   float* __restrict__ z){
  __shared__ float lw[KUP]; __shared__ int li[KUP];
  int m = blockIdx.x;
  int tid = threadIdx.x;
  if (tid < KUP){ lw[tid] = logits[(size_t)m*KUP + tid]; li[tid] = up_idx[(size_t)m*KUP + tid]; }
  __syncthreads();
  float mx = -1e30f;
  for (int k=0;k<KUP;k++) mx = fmaxf(mx, lw[k]);
  __syncthreads();
  if (tid < KUP) lw[tid] = expf(lw[tid]-mx);
  __syncthreads();
  float s = 0.f;
  for (int k=0;k<KUP;k++) s += lw[k];
  float inv = 1.f/s;
  for (int c = tid; c < 227; c += 64){
    float acc = 0.f;
    for (int k=0;k<KUP;k++) acc += lw[k] * xf[(size_t)li[k]*227 + c];
    z[(size_t)m*227 + c] = acc*inv;
  }
}

__global__ void final_k(const float* __restrict__ h, const float* __restrict__ wf,
                        const float* __restrict__ bfp, void* __restrict__ out,
                        int r0, int rows, const int* __restrict__ flag){
  int m = blockIdx.x*256 + threadIdx.x;
  if (m >= rows) return;
  float hv[16];
#pragma unroll
  for (int d=0;d<16;d++) hv[d] = h[(size_t)m*16 + d];
#pragma unroll
  for (int o=0;o<3;o++){
    float acc = 0.f;
#pragma unroll
    for (int d=0;d<16;d++) acc += hv[d]*wf[o*16+d];
    float v = acc + bfp[o];
    if (!(fabsf(v) < 1e30f)) v = 777.0f;   // NaN/inf canary
    size_t oi = (size_t)(r0+m)*3+o;
    if (flag[0]) ((bf16*)out)[oi] = __float2bfloat16(v);
    else         ((float*)out)[oi] = v;
  }
}

// ---------------------------------------------------------------------------
extern "C" void kernel_launch(void* const* d_in, const int* in_sizes, int n_in,
                              void* d_out, int out_size, void* d_ws, size_t ws_size,
                              hipStream_t stream) {
  const int *idx0  = (const int*)d_in[3];
  const int *upidx = (const int*)d_in[37];

  // ---- workspace layout (floats) ----
  float* ws = (float*)d_ws;
  float* x_feat = ws;                     // [N,227]
  float* f1b    = ws + 3602944;           // [N,128]
  float* pmax   = ws + 5634560;
  float* psum   = ws + 5667328;
  float* fmaxv  = ws + 5700096;
  float* favgv  = ws + 5700224;
  int*   flag   = (int*)(ws + 5700352);
  int*   idx1   = (int*)(ws + 5700368);   // N*5
  float* nrm    = ws + 5779728;           // N
  float* logits = ws + 5795600;           // UP_ROWS
  float* wcvt   = ws + 6508352;           // 706,020 fp32 weights
  float* S      = ws + 7214400;           // scratch arena (9,662,464 floats)
  ushort_t* whi = (ushort_t*)(S + 9662464);   // 114688 bf16 hi plane
  ushort_t* wlo = whi + 114688;               // 114688 bf16 lo plane

  const size_t NEED = (size_t)(7214400 + 9662464 + 114688) * 4;  // ~68 MB
  if (ws_size < NEED) {
    fillmark_k<<<CDIV(out_size,256),256,0,stream>>>((bf16*)d_out, out_size);
    return;
  }

  // ---- dtype flag + one-shot weight conversion to fp32 ----
  flag_k<<<1,64,0,stream>>>((const uint*)d_in[2], flag);
  CvtTab tab;
  int wcoff = 0, seg = 0;
  auto CVT = [&](int i, int n)->const float* {
    tab.src[seg] = d_in[i]; tab.start[seg] = wcoff; seg++;
    const float* p = wcvt + wcoff; wcoff += n;
    return p;
  };
  const float *E0W1=CVT(4,8960),  *E0S1=CVT(5,128),  *E0H1=CVT(6,128),
              *E0W2=CVT(7,8192),  *E0B2=CVT(8,64);
  const float *F0W1=CVT(9,43584), *F0S1=CVT(10,192), *F0H1=CVT(11,192),
              *F0W2=CVT(12,24576),*F0S2=CVT(13,128), *F0H2=CVT(14,128),
              *F0W3=CVT(15,8192), *F0S3=CVT(16,64),  *F0H3=CVT(17,64),
              *F0W4=CVT(18,4096), *F0B4=CVT(19,64);
  const float *E1W1=CVT(20,32768),*E1S1=CVT(21,256), *E1H1=CVT(22,256),
              *E1W2=CVT(23,32768),*E1B2=CVT(24,128);
  const float *F1W1=CVT(25,172032),*F1S1=CVT(26,384),*F1H1=CVT(27,384),
              *F1W2=CVT(28,98304),*F1S2=CVT(29,256), *F1H2=CVT(30,256),
              *F1W3=CVT(31,32768),*F1S3=CVT(32,128), *F1H3=CVT(33,128),
              *F1W4=CVT(34,16384),*F1B4=CVT(35,128);
  const float *UPW0=CVT(38,896),  *UPS0=CVT(39,128), *UPH0=CVT(40,128),
              *UPWR=CVT(41,114688),*UPSR=CVT(42,896),*UPHR=CVT(43,896),
              *UPWF=CVT(44,128),  *UPBF=CVT(45,1);
  const float *DW0=CVT(46,58112), *DB0=CVT(47,256),
              *DW1=CVT(48,32768), *DB1=CVT(49,128),
              *DW2=CVT(50,8192),  *DB2=CVT(51,64),
              *DW3=CVT(52,2048),  *DB3=CVT(53,32),
              *DW4=CVT(54,512),   *DB4=CVT(55,16),
              *DWF=CVT(56,48),    *DBF=CVT(57,3);
  cvt_all_k<<<CDIV(wcoff,256),256,0,stream>>>(tab, wcvt, flag, wcoff);

  // frag-major split-bf16 pack of the SIREN 128x128 weights
  packfrag_k<<<CDIV(114688,256),256,0,stream>>>(UPWR, whi, wlo, 114688);

  const float invN = 1.f/(float)N_PTS;
  const int CHP = 3072;    // edge-phase point chunk
  const int CHN = 8192;    // fc-phase row chunk
  const int CHD = 4096;    // decoder row chunk

  featin_k<<<CDIV(N_PTS*35,256),256,0,stream>>>(d_in[1], d_in[2], x_feat, flag);

  // ---- phase 1: emb block 0
  for (int n0 = 0; n0 < N_PTS; n0 += CHP) {
    int np = N_PTS - n0; if (np > CHP) np = CHP;
    int ne = np * KNN_K;
    float* eA = S;
    float* eB = S + 1075200;
    gather_e_k<<<CDIV(ne*70,256),256,0,stream>>>(x_feat, 0, 35, idx0, eA, n0, np);
    gemm_k<0,1><<<dim3(CDIV(ne,64),2),256,0,stream>>>(eA,70, E0W1,70, E0S1,E0H1,0.f, eB,128, ne,128,70);
    gemm_k<1,0><<<dim3(CDIV(ne,64),1),256,0,stream>>>(eB,128, E0W2,128, nullptr,E0B2,0.f, eA,64, ne,64,128);
    kmax_k<<<CDIV(np*64,256),256,0,stream>>>(eA, 64, f1b, n0, np);
  }
  reduce1_k<64><<<256,256,0,stream>>>(f1b, N_PTS, pmax, psum);
  reduce2_k<64><<<1,64,0,stream>>>(pmax, psum, 256, invN, fmaxv, favgv);
  for (int n0 = 0; n0 < N_PTS; n0 += CHN) {
    int np = N_PTS - n0; if (np > CHN) np = CHN;
    float* h  = S;
    float* a1 = S + 1859584;
    int gx = CDIV(np,64);
    concat_k<<<CDIV(np*227,256),256,0,stream>>>(x_feat,0,35, f1b,64, fmaxv,favgv, h, n0, np);
    gemm_k<0,1><<<dim3(gx,3),256,0,stream>>>(h,227,  F0W1,227, F0S1,F0H1,0.f, a1,192, np,192,227);
    gemm_k<0,1><<<dim3(gx,2),256,0,stream>>>(a1,192, F0W2,192, F0S2,F0H2,0.f, h,128,  np,128,192);
    gemm_k<0,1><<<dim3(gx,1),256,0,stream>>>(h,128,  F0W3,128, F0S3,F0H3,0.f, a1,64,  np,64,128);
    gemm_k<1,0><<<dim3(gx,1),256,0,stream>>>(a1,64,  F0W4,64,  nullptr,F0B4,0.f, x_feat+(size_t)n0*227+35,227, np,64,64);
  }

  // ---- phase 2: dynamic KNN (MFMA, norm-augmented split-bf16)
  norms_k<<<CDIV(N_PTS,256),256,0,stream>>>(x_feat, nrm);
  {
    const int PLANE = NTILE*5*64*8;              // 1,269,760
    ushort_t* ajhi = (ushort_t*)S;
    ushort_t* ajlo = ajhi + PLANE;
    ushort_t* bihi = ajlo + PLANE;
    ushort_t* bilo = bihi + PLANE;               // 5,079,040 ushorts < S
    packknn_k<<<CDIV(PLANE,256),256,0,stream>>>(x_feat, nrm, ajhi, ajlo, bihi, bilo);
    knn_mfma_k<<<NTILE/4,256,0,stream>>>(ajhi, ajlo, bihi, bilo, idx1);
  }

  // ---- phase 3: emb block 1
  for (int n0 = 0; n0 < N_PTS; n0 += CHP) {
    int np = N_PTS - n0; if (np > CHP) np = CHP;
    int ne = np * KNN_K;
    float* eA = S;
    float* eB = S + 1966080;
    gather_e_k<<<CDIV(ne*128,256),256,0,stream>>>(x_feat, 35, 64, idx1, eA, n0, np);
    gemm_k<0,1><<<dim3(CDIV(ne,64),4),256,0,stream>>>(eA,128, E1W1,128, E1S1,E1H1,0.f, eB,256, ne,256,128);
    gemm_k<1,0><<<dim3(CDIV(ne,64),2),256,0,stream>>>(eB,256, E1W2,256, nullptr,E1B2,0.f, eA,128, ne,128,256);
    kmax_k<<<CDIV(np*128,256),256,0,stream>>>(eA, 128, f1b, n0, np);
  }
  reduce1_k<128><<<256,256,0,stream>>>(f1b, N_PTS, pmax, psum);
  reduce2_k<128><<<1,128,0,stream>>>(pmax, psum, 256, invN, fmaxv, favgv);
  for (int n0 = 0; n0 < N_PTS; n0 += CHN) {
    int np = N_PTS - n0; if (np > CHN) np = CHN;
    float* h  = S;
    float* a1 = S + 3670016;
    int gx = CDIV(np,64);
    concat_k<<<CDIV(np*448,256),256,0,stream>>>(x_feat,35,64, f1b,128, fmaxv,favgv, h, n0, np);
    gemm_k<0,1><<<dim3(gx,6),256,0,stream>>>(h,448,  F1W1,448, F1S1,F1H1,0.f, a1,384, np,384,448);
    gemm_k<0,1><<<dim3(gx,4),256,0,stream>>>(a1,384, F1W2,384, F1S2,F1H2,0.f, h,256,  np,256,384);
    gemm_k<0,1><<<dim3(gx,2),256,0,stream>>>(h,256,  F1W3,256, F1S3,F1H3,0.f, a1,128, np,128,256);
    gemm_k<1,0><<<dim3(gx,2),256,0,stream>>>(a1,128, F1W4,128, nullptr,F1B4,0.f, x_feat+(size_t)n0*227+99,227, np,128,128);
  }

  // ---- phase 4: fused split-bf16 MFMA SIREN -> logits; softmax gather -> z
  siren_fused_k<<<CDIV(UP_ROWS,128),256,0,stream>>>(
      d_in[36], whi, wlo, UPW0, UPS0, UPH0, UPSR, UPHR, UPWF, UPBF, logits, flag);
  float* zbuf = S;                 // [M,227]
  softgather_k<<<M_PTS,64,0,stream>>>(logits, upidx, x_feat, zbuf);

  // ---- phase 5: SIREN decoder
  {
    float* A  = S + 8089600;            // [CHD,256]
    float* Bb = S + 8089600 + 1048576;  // [CHD,128]
    for (int r0 = 0; r0 < M_PTS; r0 += CHD) {
      int rows = M_PTS - r0; if (rows > CHD) rows = CHD;
      int gx = CDIV(rows,64);
      gemm_k<2,2><<<dim3(gx,4),256,0,stream>>>(zbuf + (size_t)r0*227,227, DW0,227, nullptr,DB0,30.f, A,256,  rows,256,227);
      gemm_k<1,2><<<dim3(gx,2),256,0,stream>>>(A,256,  DW1,256, nullptr,DB1,0.f, Bb,128, rows,128,256);
      gemm_k<1,2><<<dim3(gx,1),256,0,stream>>>(Bb,128, DW2,128, nullptr,DB2,0.f, A,64,   rows,64,128);
      gemm_k<1,2><<<dim3(gx,1),256,0,stream>>>(A,64,   DW3,64,  nullptr,DB3,0.f, Bb,32,  rows,32,64);
      gemm_k<1,2><<<dim3(gx,1),256,0,stream>>>(Bb,32,  DW4,32,  nullptr,DB4,0.f, A,16,   rows,16,32);
      final_k<<<CDIV(rows,256),256,0,stream>>>(A, DWF, DBF, d_out, r0, rows, flag);
    }
  }
}

// Round 7
// 2845.336 us; speedup vs baseline: 2.7226x; 1.3171x over previous
//
#include <hip/hip_runtime.h>
#include <hip/hip_bf16.h>
#include <math.h>

#define N_PTS 15872
#define M_PTS 35637
#define KNN_K 5
#define KUP   20
#define UP_ROWS (M_PTS * KUP)   // 712740
#define NTILE (N_PTS/32)        // 496 i/j tiles
#define CDIV(a,b) (((a)+(b)-1)/(b))

typedef __hip_bfloat16 bf16;
typedef unsigned int uint;
typedef unsigned short ushort_t;
__device__ __forceinline__ float b2f(bf16 x){ return __bfloat162float(x); }

// round-to-nearest-even fp32 -> bf16 bit pattern (finite inputs)
__device__ __forceinline__ uint f2bf_bits(float x){
  uint u = __float_as_uint(x);
  return (u + 0x7FFFu + ((u>>16)&1u)) >> 16;
}

typedef __attribute__((ext_vector_type(8))) short bf16x8;
typedef __attribute__((ext_vector_type(16))) float f32x16;
union FragAB { bf16x8 v; uint u[4]; };
union FragB  { bf16x8 v; uint4 q; };
union Acc16  { f32x16 v; float f[16]; };

// ---------------------------------------------------------------------------
__global__ void flag_k(const uint* __restrict__ pos_raw, int* __restrict__ flag){
  if (threadIdx.x == 0 && blockIdx.x == 0)
    flag[0] = (pos_raw[0] == 0x3F800000u) ? 1 : 0;
}

// one-shot conversion of ALL weight arrays (bf16 or fp32 per flag) to fp32
struct CvtTab { const void* src[52]; int start[52]; };
__global__ __launch_bounds__(256) void cvt_all_k(CvtTab tab, float* __restrict__ dst,
                                                 const int* __restrict__ flag, int total){
  int i = blockIdx.x*256 + threadIdx.x;
  if (i >= total) return;
  int s = 0;
#pragma unroll 1
  for (int k = 1; k < 52; k++) if (tab.start[k] <= i) s = k;
  int off = i - tab.start[s];
  float v = flag[0] ? b2f(((const bf16*)tab.src[s])[off]) : ((const float*)tab.src[s])[off];
  dst[i] = v;
}

// pack SIREN 128x128 weights into frag-major split-bf16 hi/lo planes.
__global__ void packfrag_k(const float* __restrict__ w, ushort_t* __restrict__ whi,
                           ushort_t* __restrict__ wlo, int n){
  int i = blockIdx.x*256 + threadIdx.x;
  if (i >= n) return;
  int j = i & 7;
  int lam = (i >> 3) & 63;
  int fg = i >> 9;
  int t = fg & 3, ks = (fg >> 2) & 1, Q = (fg >> 3) & 3, l = fg >> 5;
  int nn = t*32 + (lam & 31);
  int kk = Q*32 + ks*16 + (lam >> 5)*8 + j;
  float x = w[l*16384 + nn*128 + kk];
  uint hb = f2bf_bits(x);
  float hf = __uint_as_float(hb << 16);
  uint lb = f2bf_bits(x - hf);
  whi[i] = (ushort_t)hb;
  wlo[i] = (ushort_t)lb;
}

// pack KNN features into frag-major split-bf16 planes with norm augmentation.
// K=80: A-side (j): [2f, n_j, 1, 0...]; B-side (i): [f, -1, -n_i, 0...]
__global__ void packknn_k(const float* __restrict__ xf, const float* __restrict__ nr,
                          ushort_t* __restrict__ ahi, ushort_t* __restrict__ alo,
                          ushort_t* __restrict__ bhi, ushort_t* __restrict__ blo){
  int i = blockIdx.x*256 + threadIdx.x;
  if (i >= NTILE*5*64*8) return;
  int e = i & 7;
  int lane = (i >> 3) & 63;
  int rest = i >> 9;
  int kc = rest % 5, jt = rest / 5;
  int n = jt*32 + (lane & 31);
  int k = kc*16 + (lane >> 5)*8 + e;
  float f = (k < 64) ? xf[(size_t)n*227 + 35 + k] : 0.f;
  float av, bv;
  if (k < 64)      { av = 2.f*f;   bv = f; }
  else if (k == 64){ av = nr[n];   bv = -1.f; }
  else if (k == 65){ av = 1.f;     bv = -nr[n]; }
  else             { av = 0.f;     bv = 0.f; }
  uint ah = f2bf_bits(av); uint al = f2bf_bits(av - __uint_as_float(ah<<16));
  uint bh = f2bf_bits(bv); uint bl = f2bf_bits(bv - __uint_as_float(bh<<16));
  ahi[i] = (ushort_t)ah; alo[i] = (ushort_t)al;
  bhi[i] = (ushort_t)bh; blo[i] = (ushort_t)bl;
}

__global__ void fillmark_k(bf16* __restrict__ out, int n){
  int i = blockIdx.x*256 + threadIdx.x;
  if (i < n) out[i] = __float2bfloat16(12345.0f);
}

// ---------------------------------------------------------------------------
// Generic fused GEMM (fp32):  C[m,n] = ACT( EPI( sum_k A[m,k]*W[n,k] ) )
// EPI 0: v*scale[n]+shift[n]   EPI 1: v+shift[n]   EPI 2: (v+shift[n])*gmul
// ACT 0: none   ACT 1: lrelu(0.2)   ACT 2: sin
// ---------------------------------------------------------------------------
template<int EPI, int ACT>
__global__ __launch_bounds__(256) void gemm_k(
    const float* __restrict__ A, int lda,
    const float* __restrict__ W, int ldw,
    const float* __restrict__ scale, const float* __restrict__ shift,
    float gmul, float* __restrict__ C, int ldc,
    int M, int Nout, int K)
{
  __shared__ __align__(16) float As[16][64];
  __shared__ __align__(16) float Ws[16][64];
  const int tid = threadIdx.x;
  const int tx = tid & 15, ty = tid >> 4;
  const int bm = blockIdx.x * 64, bn = blockIdx.y * 64;
  const int ar = tid >> 2, ak = (tid & 3) * 4;
  float acc[4][4] = {};
  for (int k0 = 0; k0 < K; k0 += 16) {
    float a0=0.f,a1=0.f,a2=0.f,a3=0.f;
    int grow = bm + ar;
    if (grow < M) {
      const float* ap = A + (size_t)grow * lda + (k0 + ak);
      int rem = K - (k0 + ak);
      if (rem >= 4) { a0=ap[0]; a1=ap[1]; a2=ap[2]; a3=ap[3]; }
      else { if(rem>0)a0=ap[0]; if(rem>1)a1=ap[1]; if(rem>2)a2=ap[2]; }
    }
    float w0=0.f,w1=0.f,w2=0.f,w3=0.f;
    int gn = bn + ar;
    if (gn < Nout) {
      const float* wp = W + (size_t)gn * ldw + (k0 + ak);
      int rem = K - (k0 + ak);
      if (rem >= 4) { w0=wp[0]; w1=wp[1]; w2=wp[2]; w3=wp[3]; }
      else { if(rem>0)w0=wp[0]; if(rem>1)w1=wp[1]; if(rem>2)w2=wp[2]; }
    }
    __syncthreads();
    As[ak+0][ar]=a0; As[ak+1][ar]=a1; As[ak+2][ar]=a2; As[ak+3][ar]=a3;
    Ws[ak+0][ar]=w0; Ws[ak+1][ar]=w1; Ws[ak+2][ar]=w2; Ws[ak+3][ar]=w3;
    __syncthreads();
#pragma unroll
    for (int kk = 0; kk < 16; kk++) {
      float4 av = *reinterpret_cast<const float4*>(&As[kk][ty*4]);
      float4 wv = *reinterpret_cast<const float4*>(&Ws[kk][tx*4]);
      float aa[4] = {av.x,av.y,av.z,av.w};
      float ww[4] = {wv.x,wv.y,wv.z,wv.w};
#pragma unroll
      for (int i=0;i<4;i++)
#pragma unroll
        for (int j=0;j<4;j++) acc[i][j] += aa[i]*ww[j];
    }
  }
#pragma unroll
  for (int i=0;i<4;i++){
    int m = bm + ty*4 + i;
    if (m >= M) continue;
#pragma unroll
    for (int j=0;j<4;j++){
      int n = bn + tx*4 + j;
      if (n >= Nout) continue;
      float v = acc[i][j];
      if (EPI==0)      v = v * scale[n] + shift[n];
      else if (EPI==1) v = v + shift[n];
      else             v = (v + shift[n]) * gmul;
      if (ACT==1)      v = v > 0.f ? v : 0.2f*v;
      else if (ACT==2) v = sinf(v);
      C[(size_t)m*ldc + n] = v;
    }
  }
}

// ---------------------------------------------------------------------------
// MFMA KNN v2: 1 block per i-tile (4 waves), j-range split across waves
// (wave w: jt = w, w+4, ...), register double-buffered A-stream, per-wave
// register top-5, half-lane shfl merge, then cross-wave LDS merge.
// ---------------------------------------------------------------------------
#define INS5(tv, tj, v, j) \
  if ((v) > tv[4]){ tv[4]=(v); tj[4]=(j); \
    _Pragma("unroll") \
    for (int q=4;q>0;q--) \
      if (tv[q] > tv[q-1]){ float tf=tv[q-1]; tv[q-1]=tv[q]; tv[q]=tf; \
                            int ti=tj[q-1]; tj[q-1]=tj[q]; tj[q]=ti; } }

__global__ __launch_bounds__(256) void knn_mfma_k(
    const ushort_t* __restrict__ ahi, const ushort_t* __restrict__ alo,
    const ushort_t* __restrict__ bhi, const ushort_t* __restrict__ blo,
    int* __restrict__ out)
{
  __shared__ float mv[4][32][5];
  __shared__ int   mjj[4][32][5];
  const int tid = threadIdx.x;
  const int lane = tid & 63;
  const int wv = tid >> 6;               // 0..3: j-partition
  const int np = lane & 31;
  const int hb2 = lane >> 5;
  const int it = blockIdx.x;             // i-tile
  const int ig = it*32 + np;

  // i-side (B) frags: register-resident for the whole kernel
  FragB vh[5], vl[5];
  {
    size_t bb = (size_t)(it*5)*512 + (size_t)lane*8;
#pragma unroll
    for (int kc=0;kc<5;kc++){
      vh[kc].q = *(const uint4*)(bhi + bb + kc*512);
      vl[kc].q = *(const uint4*)(blo + bb + kc*512);
    }
  }

  float tv[5] = {-1e30f,-1e30f,-1e30f,-1e30f,-1e30f};
  int   tj[5] = {0,0,0,0,0};

  // double-buffered A-stream: preload first tile of this wave's partition
  FragB uh[5], ul[5], nh[5], nl[5];
  {
    size_t ab = (size_t)(wv*5)*512 + (size_t)lane*8;
#pragma unroll
    for (int kc=0;kc<5;kc++){
      uh[kc].q = *(const uint4*)(ahi + ab + kc*512);
      ul[kc].q = *(const uint4*)(alo + ab + kc*512);
    }
  }

#pragma unroll 1
  for (int t = 0; t < NTILE/4; t++){
    int jt = wv + t*4;
    if (t+1 < NTILE/4){
      size_t an = (size_t)((jt+4)*5)*512 + (size_t)lane*8;
#pragma unroll
      for (int kc=0;kc<5;kc++){
        nh[kc].q = *(const uint4*)(ahi + an + kc*512);
        nl[kc].q = *(const uint4*)(alo + an + kc*512);
      }
    }
    Acc16 acc;
#pragma unroll
    for (int q=0;q<16;q++) acc.f[q] = 0.f;
#pragma unroll
    for (int kc=0;kc<5;kc++){
      acc.v = __builtin_amdgcn_mfma_f32_32x32x16_bf16(uh[kc].v, vh[kc].v, acc.v, 0,0,0);
      acc.v = __builtin_amdgcn_mfma_f32_32x32x16_bf16(ul[kc].v, vh[kc].v, acc.v, 0,0,0);
      acc.v = __builtin_amdgcn_mfma_f32_32x32x16_bf16(uh[kc].v, vl[kc].v, acc.v, 0,0,0);
    }
    int jb = jt*32 + 4*hb2;
#pragma unroll
    for (int reg=0;reg<16;reg++){
      int j = jb + (reg&3) + 8*(reg>>2);
      float v = acc.f[reg];
      if (j != ig) { INS5(tv, tj, v, j); }
    }
    if (t+1 < NTILE/4){
#pragma unroll
      for (int kc=0;kc<5;kc++){ uh[kc] = nh[kc]; ul[kc] = nl[kc]; }
    }
  }

  // merge the two half-lane lists (same i, disjoint j)
#pragma unroll
  for (int s=0;s<5;s++){
    float ov = __shfl_xor(tv[s], 32, 64);
    int   oj = __shfl_xor(tj[s], 32, 64);
    INS5(tv, tj, ov, oj);
  }
  // cross-wave merge via LDS
  if (hb2 == 0){
#pragma unroll
    for (int s=0;s<5;s++){ mv[wv][np][s] = tv[s]; mjj[wv][np][s] = tj[s]; }
  }
  __syncthreads();
  if (tid < 32){
    float bv[5]; int bj[5];
#pragma unroll
    for (int s=0;s<5;s++){ bv[s] = mv[0][tid][s]; bj[s] = mjj[0][tid][s]; }
#pragma unroll
    for (int w=1;w<4;w++)
#pragma unroll
      for (int s=0;s<5;s++){
        float v = mv[w][tid][s]; int j = mjj[w][tid][s];
        INS5(bv, bj, v, j);
      }
    int gi = it*32 + tid;
#pragma unroll
    for (int s=0;s<5;s++) out[gi*KNN_K + s] = bj[s];
  }
}

// ---------------------------------------------------------------------------
// Fused 8-layer SIREN + head, split-bf16 MFMA (validated round 5).
// ---------------------------------------------------------------------------
__global__ __launch_bounds__(256, 2) void siren_fused_k(
    const void* __restrict__ upin,
    const ushort_t* __restrict__ whi, const ushort_t* __restrict__ wlo,
    const float* __restrict__ W0c, const float* __restrict__ S0c, const float* __restrict__ H0c,
    const float* __restrict__ SRc, const float* __restrict__ HRc,
    const float* __restrict__ WFc, const float* __restrict__ BFc,
    float* __restrict__ logits, const int* __restrict__ flag)
{
  __shared__ __align__(16) uint act[4*32*128];
  __shared__ float intile[4*32*8];
  __shared__ float w0s[128*9];
  __shared__ float wfs[128];
  __shared__ float bfs[1];

  const int tid  = threadIdx.x;
  const int lane = tid & 63;
  const int wv   = tid >> 6;
  const int np   = lane & 31;
  const int hb2  = lane >> 5;
  const int rowbase = blockIdx.x * 128 + wv * 32;
  const int isbf = flag[0];
  uint*  actw = act + wv*32*128;
  float* intw = intile + wv*32*8;

  for (int e = tid; e < 128*7; e += 256) w0s[(e/7)*9 + (e%7)] = W0c[e];
  if (tid < 128) wfs[tid] = WFc[tid];
  if (tid == 0) bfs[0] = BFc[0];
  for (int e = lane; e < 32*7; e += 64) {
    int r = e/7, k = e%7;
    int gr = rowbase + r;
    float v = 0.f;
    if (gr < UP_ROWS)
      v = isbf ? b2f(((const bf16*)upin)[(size_t)gr*7+k]) : ((const float*)upin)[(size_t)gr*7+k];
    intw[r*8+k] = v;
  }
  __syncthreads();

#pragma unroll
  for (int t = 0; t < 4; t++) {
    int c = t*32 + np;
    float s = S0c[c], b = H0c[c];
#pragma unroll
    for (int reg = 0; reg < 16; reg++) {
      int r = (reg&3) + 8*(reg>>2) + 4*hb2;
      float a = 0.f;
#pragma unroll
      for (int k = 0; k < 7; k++) a += intw[r*8+k]*w0s[c*9+k];
      float x = __sinf(a*s + b);
      uint hbi = f2bf_bits(x);
      uint lbi = f2bf_bits(x - __uint_as_float(hbi<<16));
      int col = (c & 3) | ((((c>>2) ^ r) & 31) << 2);
      actw[r*128 + col] = (hbi<<16) | lbi;
    }
  }

  for (int l = 0; l < 7; l++) {
    float sc[4], sh[4];
#pragma unroll
    for (int t=0;t<4;t++){ sc[t] = SRc[l*128 + t*32 + np]; sh[t] = HRc[l*128 + t*32 + np]; }
    Acc16 acc[4];
#pragma unroll
    for (int t=0;t<4;t++)
#pragma unroll
      for (int i=0;i<16;i++) acc[t].f[i] = 0.f;

#pragma unroll 1
    for (int Q = 0; Q < 4; Q++) {
#pragma unroll
      for (int ks = 0; ks < 2; ks++) {
        int g0 = (Q*32 + ks*16 + hb2*8) >> 2;
        uint4 a0 = *(const uint4*)&actw[np*128 + ((g0 ^ np) << 2)];
        uint4 a1 = *(const uint4*)&actw[np*128 + (((g0+1) ^ np) << 2)];
        uint au[8] = {a0.x,a0.y,a0.z,a0.w,a1.x,a1.y,a1.z,a1.w};
        FragAB ahi, alo;
#pragma unroll
        for (int p=0;p<4;p++){
          ahi.u[p] = (au[2*p]>>16)     | (au[2*p+1] & 0xFFFF0000u);
          alo.u[p] = (au[2*p]&0xFFFFu) | (au[2*p+1]<<16);
        }
        size_t fb = ((size_t)(((l*4 + Q)*2 + ks)*4) << 9) + (size_t)lane*8;
        FragB bh[4], bl[4];
#pragma unroll
        for (int t=0;t<4;t++){
          bh[t].q = *(const uint4*)(whi + fb + (size_t)t*512);
          bl[t].q = *(const uint4*)(wlo + fb + (size_t)t*512);
        }
#pragma unroll
        for (int t=0;t<4;t++){
          acc[t].v = __builtin_amdgcn_mfma_f32_32x32x16_bf16(ahi.v, bh[t].v, acc[t].v, 0,0,0);
          acc[t].v = __builtin_amdgcn_mfma_f32_32x32x16_bf16(alo.v, bh[t].v, acc[t].v, 0,0,0);
          acc[t].v = __builtin_amdgcn_mfma_f32_32x32x16_bf16(ahi.v, bl[t].v, acc[t].v, 0,0,0);
        }
      }
    }
#pragma unroll
    for (int t=0;t<4;t++){
      int c = t*32 + np;
#pragma unroll
      for (int reg=0;reg<16;reg++){
        int r = (reg&3) + 8*(reg>>2) + 4*hb2;
        float x = __sinf(acc[t].f[reg]*sc[t] + sh[t]);
        uint hbi = f2bf_bits(x);
        uint lbi = f2bf_bits(x - __uint_as_float(hbi<<16));
        int col = (c & 3) | ((((c>>2) ^ r) & 31) << 2);
        actw[r*128 + col] = (hbi<<16) | lbi;
      }
    }
    __syncthreads();
  }

  {
    float a = 0.f;
#pragma unroll
    for (int g = 0; g < 16; g++) {
      int gg = hb2*16 + g;
      uint4 u = *(const uint4*)&actw[np*128 + ((gg ^ np) << 2)];
      int kb = gg*4;
      float x0 = __uint_as_float(u.x & 0xFFFF0000u) + __uint_as_float(u.x<<16);
      float x1 = __uint_as_float(u.y & 0xFFFF0000u) + __uint_as_float(u.y<<16);
      float x2 = __uint_as_float(u.z & 0xFFFF0000u) + __uint_as_float(u.z<<16);
      float x3 = __uint_as_float(u.w & 0xFFFF0000u) + __uint_as_float(u.w<<16);
      a += x0*wfs[kb] + x1*wfs[kb+1] + x2*wfs[kb+2] + x3*wfs[kb+3];
    }
    a += __shfl_xor(a, 32, 64);
    int gr = rowbase + np;
    if (hb2 == 0 && gr < UP_ROWS) logits[gr] = a + bfs[0];
  }
}

// ---------------------------------------------------------------------------
__global__ void featin_k(const void* __restrict__ ldx, const void* __restrict__ pos,
                         float* __restrict__ xf, const int* __restrict__ flag){
  int i = blockIdx.x*256 + threadIdx.x;
  if (i >= N_PTS*35) return;
  int n = i / 35, c = i % 35;
  float v;
  if (flag[0]) {
    v = (c < 3) ? b2f(((const bf16*)ldx)[n*3+c]) : b2f(((const bf16*)pos)[n*32 + (c-3)]);
  } else {
    v = (c < 3) ? ((const float*)ldx)[n*3+c] : ((const float*)pos)[n*32 + (c-3)];
  }
  xf[(size_t)n*227 + c] = v;
}

__global__ void gather_e_k(const float* __restrict__ xf, int coff, int CIN,
                           const int* __restrict__ idx, float* __restrict__ e,
                           int n0, int np){
  int W2 = 2*CIN;
  int i = blockIdx.x*256 + threadIdx.x;
  if (i >= np*KNN_K*W2) return;
  int c = i % W2; int ek = i / W2;
  int nl = ek / KNN_K, k = ek % KNN_K;
  int n = n0 + nl;
  int j = idx[n*KNN_K + k];
  float out;
  if (c < CIN) out = xf[(size_t)j*227 + coff + c] - xf[(size_t)n*227 + coff + c];
  else         out = xf[(size_t)n*227 + coff + (c-CIN)];
  e[(size_t)ek*W2 + c] = out;
}

__global__ void kmax_k(const float* __restrict__ e2, int C, float* __restrict__ f1,
                       int n0, int np){
  int i = blockIdx.x*256 + threadIdx.x;
  if (i >= np*C) return;
  int nl = i / C, c = i % C;
  float v = -1e30f;
  for (int k=0;k<KNN_K;k++) v = fmaxf(v, e2[((size_t)nl*KNN_K+k)*C + c]);
  f1[(size_t)(n0+nl)*C + c] = v;
}

template<int C>
__global__ __launch_bounds__(256) void reduce1_k(const float* __restrict__ X, int n,
                                                 float* __restrict__ pmax, float* __restrict__ psum){
  const int tid = threadIdx.x;
  const int c = tid % C;
  const int r0 = tid / C;
  const int TPR = 256 / C;
  float vmax = -1e30f, vsum = 0.f;
  for (int row = blockIdx.x * TPR + r0; row < n; row += gridDim.x * TPR) {
    float v = X[(size_t)row * C + c];
    vmax = fmaxf(vmax, v); vsum += v;
  }
  __shared__ float smax[256], ssum[256];
  smax[tid]=vmax; ssum[tid]=vsum;
  __syncthreads();
  if (tid < C) {
    for (int q=1;q<TPR;q++){ vmax=fmaxf(vmax, smax[q*C+c]); vsum += ssum[q*C+c]; }
    pmax[blockIdx.x*C + c] = vmax; psum[blockIdx.x*C + c] = vsum;
  }
}

template<int C>
__global__ void reduce2_k(const float* __restrict__ pmax, const float* __restrict__ psum,
                          int nblk, float invn, float* __restrict__ fmaxo, float* __restrict__ favgo){
  int c = threadIdx.x; if (c >= C) return;
  float vmax=-1e30f, vsum=0.f;
  for (int b=0;b<nblk;b++){ vmax=fmaxf(vmax,pmax[b*C+c]); vsum+=psum[b*C+c]; }
  fmaxo[c]=vmax; favgo[c]=vsum*invn;
}

__global__ void concat_k(const float* __restrict__ xf, int coff, int CF,
                         const float* __restrict__ f1, int C,
                         const float* __restrict__ fmax, const float* __restrict__ favg,
                         float* __restrict__ h, int n0, int np){
  int W = CF + 3*C;
  int i = blockIdx.x*256 + threadIdx.x;
  if (i >= np*W) return;
  int nl = i / W, c = i % W;
  int n = n0 + nl;
  float v;
  if (c < CF)          v = xf[(size_t)n*227 + coff + c];
  else if (c < CF+C)   v = f1[(size_t)n*C + (c-CF)];
  else if (c < CF+2*C) v = fmax[c-CF-C];
  else                 v = favg[c-CF-2*C];
  h[(size_t)nl*W + c] = v;
}

__global__ void norms_k(const float* __restrict__ xf, float* __restrict__ nr){
  int n = blockIdx.x*256 + threadIdx.x;
  if (n >= N_PTS) return;
  const float* p = xf + (size_t)n*227 + 35;
  float s = 0.f;
  for (int d=0;d<64;d++) s += p[d]*p[d];
  nr[n] = s;
}

__global__ __launch_bounds__(64) void softgather_k(const float* __restrict__ logits,
                                                   const int* __restrict__ up_idx,
                                                   const float* __restrict__ xf,
                                                   float* __restrict__ z){
  __shared__ float lw[KUP]; __shared__ int li[KUP];
  int m = blockIdx.x;
  int tid = threadIdx.x;
  if (tid < KUP){ lw[tid] = logits[(size_t)m*KUP + tid]; li[tid] = up_idx[(size_t)m*KUP + tid]; }
  __syncthreads();
  float mx = -1e30f;
  for (int k=0;k<KUP;k++) mx = fmaxf(mx, lw[k]);
  __syncthreads();
  if (tid < KUP) lw[tid] = expf(lw[tid]-mx);
  __syncthreads();
  float s = 0.f;
  for (int k=0;k<KUP;k++) s += lw[k];
  float inv = 1.f/s;
  for (int c = tid; c < 227; c += 64){
    float acc = 0.f;
    for (int k=0;k<KUP;k++) acc += lw[k] * xf[(size_t)li[k]*227 + c];
    z[(size_t)m*227 + c] = acc*inv;
  }
}

__global__ void final_k(const float* __restrict__ h, const float* __restrict__ wf,
                        const float* __restrict__ bfp, void* __restrict__ out,
                        int r0, int rows, const int* __restrict__ flag){
  int m = blockIdx.x*256 + threadIdx.x;
  if (m >= rows) return;
  float hv[16];
#pragma unroll
  for (int d=0;d<16;d++) hv[d] = h[(size_t)m*16 + d];
#pragma unroll
  for (int o=0;o<3;o++){
    float acc = 0.f;
#pragma unroll
    for (int d=0;d<16;d++) acc += hv[d]*wf[o*16+d];
    float v = acc + bfp[o];
    if (!(fabsf(v) < 1e30f)) v = 777.0f;   // NaN/inf canary
    size_t oi = (size_t)(r0+m)*3+o;
    if (flag[0]) ((bf16*)out)[oi] = __float2bfloat16(v);
    else         ((float*)out)[oi] = v;
  }
}

// ---------------------------------------------------------------------------
extern "C" void kernel_launch(void* const* d_in, const int* in_sizes, int n_in,
                              void* d_out, int out_size, void* d_ws, size_t ws_size,
                              hipStream_t stream) {
  const int *idx0  = (const int*)d_in[3];
  const int *upidx = (const int*)d_in[37];

  // ---- workspace layout (floats) ----
  float* ws = (float*)d_ws;
  float* x_feat = ws;                     // [N,227]
  float* f1b    = ws + 3602944;           // [N,128]
  float* pmax   = ws + 5634560;
  float* psum   = ws + 5667328;
  float* fmaxv  = ws + 5700096;
  float* favgv  = ws + 5700224;
  int*   flag   = (int*)(ws + 5700352);
  int*   idx1   = (int*)(ws + 5700368);   // N*5
  float* nrm    = ws + 5779728;           // N
  float* logits = ws + 5795600;           // UP_ROWS
  float* wcvt   = ws + 6508352;           // 706,020 fp32 weights
  float* S      = ws + 7214400;           // scratch arena (9,662,464 floats)
  ushort_t* whi = (ushort_t*)(S + 9662464);   // 114688 bf16 hi plane
  ushort_t* wlo = whi + 114688;               // 114688 bf16 lo plane

  const size_t NEED = (size_t)(7214400 + 9662464 + 114688) * 4;  // ~68 MB
  if (ws_size < NEED) {
    fillmark_k<<<CDIV(out_size,256),256,0,stream>>>((bf16*)d_out, out_size);
    return;
  }

  // ---- dtype flag + one-shot weight conversion to fp32 ----
  flag_k<<<1,64,0,stream>>>((const uint*)d_in[2], flag);
  CvtTab tab;
  int wcoff = 0, seg = 0;
  auto CVT = [&](int i, int n)->const float* {
    tab.src[seg] = d_in[i]; tab.start[seg] = wcoff; seg++;
    const float* p = wcvt + wcoff; wcoff += n;
    return p;
  };
  const float *E0W1=CVT(4,8960),  *E0S1=CVT(5,128),  *E0H1=CVT(6,128),
              *E0W2=CVT(7,8192),  *E0B2=CVT(8,64);
  const float *F0W1=CVT(9,43584), *F0S1=CVT(10,192), *F0H1=CVT(11,192),
              *F0W2=CVT(12,24576),*F0S2=CVT(13,128), *F0H2=CVT(14,128),
              *F0W3=CVT(15,8192), *F0S3=CVT(16,64),  *F0H3=CVT(17,64),
              *F0W4=CVT(18,4096), *F0B4=CVT(19,64);
  const float *E1W1=CVT(20,32768),*E1S1=CVT(21,256), *E1H1=CVT(22,256),
              *E1W2=CVT(23,32768),*E1B2=CVT(24,128);
  const float *F1W1=CVT(25,172032),*F1S1=CVT(26,384),*F1H1=CVT(27,384),
              *F1W2=CVT(28,98304),*F1S2=CVT(29,256), *F1H2=CVT(30,256),
              *F1W3=CVT(31,32768),*F1S3=CVT(32,128), *F1H3=CVT(33,128),
              *F1W4=CVT(34,16384),*F1B4=CVT(35,128);
  const float *UPW0=CVT(38,896),  *UPS0=CVT(39,128), *UPH0=CVT(40,128),
              *UPWR=CVT(41,114688),*UPSR=CVT(42,896),*UPHR=CVT(43,896),
              *UPWF=CVT(44,128),  *UPBF=CVT(45,1);
  const float *DW0=CVT(46,58112), *DB0=CVT(47,256),
              *DW1=CVT(48,32768), *DB1=CVT(49,128),
              *DW2=CVT(50,8192),  *DB2=CVT(51,64),
              *DW3=CVT(52,2048),  *DB3=CVT(53,32),
              *DW4=CVT(54,512),   *DB4=CVT(55,16),
              *DWF=CVT(56,48),    *DBF=CVT(57,3);
  cvt_all_k<<<CDIV(wcoff,256),256,0,stream>>>(tab, wcvt, flag, wcoff);

  // frag-major split-bf16 pack of the SIREN 128x128 weights
  packfrag_k<<<CDIV(114688,256),256,0,stream>>>(UPWR, whi, wlo, 114688);

  const float invN = 1.f/(float)N_PTS;
  const int CHP = 3072;    // edge-phase point chunk
  const int CHN = 8192;    // fc-phase row chunk
  const int CHD = 4096;    // decoder row chunk

  featin_k<<<CDIV(N_PTS*35,256),256,0,stream>>>(d_in[1], d_in[2], x_feat, flag);

  // ---- phase 1: emb block 0
  for (int n0 = 0; n0 < N_PTS; n0 += CHP) {
    int np = N_PTS - n0; if (np > CHP) np = CHP;
    int ne = np * KNN_K;
    float* eA = S;
    float* eB = S + 1075200;
    gather_e_k<<<CDIV(ne*70,256),256,0,stream>>>(x_feat, 0, 35, idx0, eA, n0, np);
    gemm_k<0,1><<<dim3(CDIV(ne,64),2),256,0,stream>>>(eA,70, E0W1,70, E0S1,E0H1,0.f, eB,128, ne,128,70);
    gemm_k<1,0><<<dim3(CDIV(ne,64),1),256,0,stream>>>(eB,128, E0W2,128, nullptr,E0B2,0.f, eA,64, ne,64,128);
    kmax_k<<<CDIV(np*64,256),256,0,stream>>>(eA, 64, f1b, n0, np);
  }
  reduce1_k<64><<<256,256,0,stream>>>(f1b, N_PTS, pmax, psum);
  reduce2_k<64><<<1,64,0,stream>>>(pmax, psum, 256, invN, fmaxv, favgv);
  for (int n0 = 0; n0 < N_PTS; n0 += CHN) {
    int np = N_PTS - n0; if (np > CHN) np = CHN;
    float* h  = S;
    float* a1 = S + 1859584;
    int gx = CDIV(np,64);
    concat_k<<<CDIV(np*227,256),256,0,stream>>>(x_feat,0,35, f1b,64, fmaxv,favgv, h, n0, np);
    gemm_k<0,1><<<dim3(gx,3),256,0,stream>>>(h,227,  F0W1,227, F0S1,F0H1,0.f, a1,192, np,192,227);
    gemm_k<0,1><<<dim3(gx,2),256,0,stream>>>(a1,192, F0W2,192, F0S2,F0H2,0.f, h,128,  np,128,192);
    gemm_k<0,1><<<dim3(gx,1),256,0,stream>>>(h,128,  F0W3,128, F0S3,F0H3,0.f, a1,64,  np,64,128);
    gemm_k<1,0><<<dim3(gx,1),256,0,stream>>>(a1,64,  F0W4,64,  nullptr,F0B4,0.f, x_feat+(size_t)n0*227+35,227, np,64,64);
  }

  // ---- phase 2: dynamic KNN (MFMA, norm-augmented split-bf16)
  norms_k<<<CDIV(N_PTS,256),256,0,stream>>>(x_feat, nrm);
  {
    const int PLANE = NTILE*5*64*8;              // 1,269,760
    ushort_t* ajhi = (ushort_t*)S;
    ushort_t* ajlo = ajhi + PLANE;
    ushort_t* bihi = ajlo + PLANE;
    ushort_t* bilo = bihi + PLANE;               // 5,079,040 ushorts < S
    packknn_k<<<CDIV(PLANE,256),256,0,stream>>>(x_feat, nrm, ajhi, ajlo, bihi, bilo);
    knn_mfma_k<<<NTILE,256,0,stream>>>(ajhi, ajlo, bihi, bilo, idx1);
  }

  // ---- phase 3: emb block 1
  for (int n0 = 0; n0 < N_PTS; n0 += CHP) {
    int np = N_PTS - n0; if (np > CHP) np = CHP;
    int ne = np * KNN_K;
    float* eA = S;
    float* eB = S + 1966080;
    gather_e_k<<<CDIV(ne*128,256),256,0,stream>>>(x_feat, 35, 64, idx1, eA, n0, np);
    gemm_k<0,1><<<dim3(CDIV(ne,64),4),256,0,stream>>>(eA,128, E1W1,128, E1S1,E1H1,0.f, eB,256, ne,256,128);
    gemm_k<1,0><<<dim3(CDIV(ne,64),2),256,0,stream>>>(eB,256, E1W2,256, nullptr,E1B2,0.f, eA,128, ne,128,256);
    kmax_k<<<CDIV(np*128,256),256,0,stream>>>(eA, 128, f1b, n0, np);
  }
  reduce1_k<128><<<256,256,0,stream>>>(f1b, N_PTS, pmax, psum);
  reduce2_k<128><<<1,128,0,stream>>>(pmax, psum, 256, invN, fmaxv, favgv);
  for (int n0 = 0; n0 < N_PTS; n0 += CHN) {
    int np = N_PTS - n0; if (np > CHN) np = CHN;
    float* h  = S;
    float* a1 = S + 3670016;
    int gx = CDIV(np,64);
    concat_k<<<CDIV(np*448,256),256,0,stream>>>(x_feat,35,64, f1b,128, fmaxv,favgv, h, n0, np);
    gemm_k<0,1><<<dim3(gx,6),256,0,stream>>>(h,448,  F1W1,448, F1S1,F1H1,0.f, a1,384, np,384,448);
    gemm_k<0,1><<<dim3(gx,4),256,0,stream>>>(a1,384, F1W2,384, F1S2,F1H2,0.f, h,256,  np,256,384);
    gemm_k<0,1><<<dim3(gx,2),256,0,stream>>>(h,256,  F1W3,256, F1S3,F1H3,0.f, a1,128, np,128,256);
    gemm_k<1,0><<<dim3(gx,2),256,0,stream>>>(a1,128, F1W4,128, nullptr,F1B4,0.f, x_feat+(size_t)n0*227+99,227, np,128,128);
  }

  // ---- phase 4: fused split-bf16 MFMA SIREN -> logits; softmax gather -> z
  siren_fused_k<<<CDIV(UP_ROWS,128),256,0,stream>>>(
      d_in[36], whi, wlo, UPW0, UPS0, UPH0, UPSR, UPHR, UPWF, UPBF, logits, flag);
  float* zbuf = S;                 // [M,227]
  softgather_k<<<M_PTS,64,0,stream>>>(logits, upidx, x_feat, zbuf);

  // ---- phase 5: SIREN decoder
  {
    float* A  = S + 8089600;            // [CHD,256]
    float* Bb = S + 8089600 + 1048576;  // [CHD,128]
    for (int r0 = 0; r0 < M_PTS; r0 += CHD) {
      int rows = M_PTS - r0; if (rows > CHD) rows = CHD;
      int gx = CDIV(rows,64);
      gemm_k<2,2><<<dim3(gx,4),256,0,stream>>>(zbuf + (size_t)r0*227,227, DW0,227, nullptr,DB0,30.f, A,256,  rows,256,227);
      gemm_k<1,2><<<dim3(gx,2),256,0,stream>>>(A,256,  DW1,256, nullptr,DB1,0.f, Bb,128, rows,128,256);
      gemm_k<1,2><<<dim3(gx,1),256,0,stream>>>(Bb,128, DW2,128, nullptr,DB2,0.f, A,64,   rows,64,128);
      gemm_k<1,2><<<dim3(gx,1),256,0,stream>>>(A,64,   DW3,64,  nullptr,DB3,0.f, Bb,32,  rows,32,64);
      gemm_k<1,2><<<dim3(gx,1),256,0,stream>>>(Bb,32,  DW4,32,  nullptr,DB4,0.f, A,16,   rows,16,32);
      final_k<<<CDIV(rows,256),256,0,stream>>>(A, DWF, DBF, d_out, r0, rows, flag);
    }
  }
}